// Round 2
// baseline (1074.664 us; speedup 1.0000x reference)
//
#include <hip/hip_runtime.h>

#define NPIX 36864   // 192*192

typedef __attribute__((ext_vector_type(8))) short short8;
typedef __attribute__((ext_vector_type(4))) float float4v;

__device__ inline unsigned short f2b(float x) {
    unsigned int u = __float_as_uint(x);
    unsigned int r = (u + 0x7FFFu + ((u >> 16) & 1u)) >> 16;
    return (unsigned short)r;
}
__device__ inline float b2f(unsigned short h) {
    return __uint_as_float(((unsigned int)h) << 16);
}

// ---------------------------------------------------------------- weight prepass
// Converts all weights to bf16 in MFMA-friendly layouts inside wbuf (shorts):
//  [0      ) dw_w2 [256][64]        n=16384
//  [16384  ) dw_w3 [576][256]       n=147456
//  [163840 ) pw_w2 [256][64]        n=16384
//  [180224 ) pw_w3 [192][256]       n=49152
//  [229376 ) sigW1t [9][64][64]     n=36864   (tap-major)
//  [266240 ) sigW2t [9][64][64]     n=36864
//  [303104 ) sigW3t [9][16][64]     n=9216    (oc padded 2->16 with zeros)
#define WB_TOTAL 312320
__global__ __launch_bounds__(256) void prep_w(
    const float* __restrict__ dw2, const float* __restrict__ dw3,
    const float* __restrict__ pw2, const float* __restrict__ pw3,
    const float* __restrict__ sw1, const float* __restrict__ sw2,
    const float* __restrict__ sw3, unsigned short* __restrict__ wb)
{
    int i = blockIdx.x * 256 + threadIdx.x;
    if (i >= WB_TOTAL) return;
    unsigned short v;
    if (i < 16384)        v = f2b(dw2[i]);
    else if (i < 163840)  v = f2b(dw3[i - 16384]);
    else if (i < 180224)  v = f2b(pw2[i - 163840]);
    else if (i < 229376)  v = f2b(pw3[i - 180224]);
    else if (i < 266240) { int j = i - 229376; int t = j / 4096, r = j % 4096, oc = r / 64, ic = r % 64;
                           v = f2b(sw1[(oc * 64 + ic) * 9 + t]); }
    else if (i < 303104) { int j = i - 266240; int t = j / 4096, r = j % 4096, oc = r / 64, ic = r % 64;
                           v = f2b(sw2[(oc * 64 + ic) * 9 + t]); }
    else                 { int j = i - 303104; int t = j / 1024, r = j % 1024, oc = r / 64, ic = r % 64;
                           v = (oc < 2) ? f2b(sw3[(oc * 64 + ic) * 9 + t]) : (unsigned short)0; }
    wb[i] = v;
}

// ---------------------------------------------------------------- layer-1 1x1 (3 -> 64), out pixel-major bf16
__global__ __launch_bounds__(256) void l1_k(
    const float* __restrict__ pose, const float* __restrict__ w,
    const float* __restrict__ bias, unsigned short* __restrict__ out)
{
    int px = blockIdx.x * 256 + threadIdx.x;
    float p0 = pose[px], p1 = pose[NPIX + px], p2 = pose[2 * NPIX + px];
    unsigned int pk[32];
    #pragma unroll
    for (int c = 0; c < 64; ++c) {
        float v = bias[c] + w[c * 3] * p0 + w[c * 3 + 1] * p1 + w[c * 3 + 2] * p2;
        v = fmaxf(v, 0.f);
        unsigned short u = f2b(v);
        if (c & 1) pk[c >> 1] |= ((unsigned int)u) << 16; else pk[c >> 1] = u;
    }
    uint4* o = (uint4*)&out[(size_t)px * 64];
    #pragma unroll
    for (int q = 0; q < 8; ++q) o[q] = ((uint4*)pk)[q];
}

// ---------------------------------------------------------------- bf16 MFMA GEMM for 1x1 convs
// act: [NPIX][K] bf16 (pixel-major), wgt: [OCtot][K] bf16, out: [NPIX][octot] bf16
// block = 64 px x 64 oc; grid = (NPIX/64, octot/64)
template<int K>
__global__ __launch_bounds__(256) void gemm1x1(
    const unsigned short* __restrict__ act, const unsigned short* __restrict__ wgt,
    const float* __restrict__ bias, unsigned short* __restrict__ out,
    int octot, int relu)
{
    constexpr int KP = K + 8;            // padded stride (shorts), keeps 16B align + 2-way banks
    __shared__ unsigned short Bs[64 * KP];
    const int tid = threadIdx.x;
    const int px0 = blockIdx.x * 64;
    const int oc0 = blockIdx.y * 64;
    for (int idx = tid; idx < 64 * (K / 8); idx += 256) {
        int p = idx / (K / 8), ko = (idx % (K / 8)) * 8;
        *(short8*)&Bs[p * KP + ko] = *(const short8*)&act[(size_t)(px0 + p) * K + ko];
    }
    __syncthreads();
    const int w = tid >> 6, l = tid & 63;
    const int ln = l & 15, lkg = l >> 4, lk = lkg * 8;
    float4v acc[4] = {{0,0,0,0},{0,0,0,0},{0,0,0,0},{0,0,0,0}};
    const int ocA = oc0 + w * 16 + ln;
    #pragma unroll
    for (int kc = 0; kc < K; kc += 32) {
        short8 a = *(const short8*)&wgt[(size_t)ocA * K + kc + lk];
        #pragma unroll
        for (int nt = 0; nt < 4; ++nt) {
            short8 b = *(const short8*)&Bs[(nt * 16 + ln) * KP + kc + lk];
            acc[nt] = __builtin_amdgcn_mfma_f32_16x16x32_bf16(a, b, acc[nt], 0, 0, 0);
        }
    }
    #pragma unroll
    for (int nt = 0; nt < 4; ++nt) {
        int px = px0 + nt * 16 + ln;
        int oc = oc0 + w * 16 + lkg * 4;
        float v0 = acc[nt][0] + bias[oc + 0];
        float v1 = acc[nt][1] + bias[oc + 1];
        float v2 = acc[nt][2] + bias[oc + 2];
        float v3 = acc[nt][3] + bias[oc + 3];
        if (relu) { v0 = fmaxf(v0, 0.f); v1 = fmaxf(v1, 0.f); v2 = fmaxf(v2, 0.f); v3 = fmaxf(v3, 0.f); }
        uint2 pk;
        pk.x = (unsigned int)f2b(v0) | (((unsigned int)f2b(v1)) << 16);
        pk.y = (unsigned int)f2b(v2) | (((unsigned int)f2b(v3)) << 16);
        *(uint2*)&out[(size_t)px * octot + oc] = pk;
    }
}

// ---------------------------------------------------------------- bf16 MFMA 3x3 conv (implicit im2col)
// act: [B][NPIX][64] bf16 pixel-major; wgt: [9][OCP][64] bf16 tap-major; out: [B][NPIX][ocw] bf16
// MT=4: 64 outch per block (wave = m-tile). MT=1: 16 outch (wave = n-tile), only oc<2 stored.
// block covers 64 px of one image row; grid.x = 3 * 192 * B
template<int MT>
__global__ __launch_bounds__(256) void conv3x3_mfma(
    const unsigned short* __restrict__ act, const unsigned short* __restrict__ wgt,
    const float* __restrict__ bias, unsigned short* __restrict__ out,
    int ocw, int relu)
{
    constexpr int SP = 72;               // ic stride (shorts): 16B aligned, 2-way banks
    constexpr int OCP = MT * 16;
    __shared__ unsigned short Bs[3 * 66 * SP];
    const int tid = threadIdx.x;
    int bx = blockIdx.x;
    const int xt = bx % 3; bx /= 3;
    const int y = bx % 192; const int b = bx / 192;
    const int x0 = xt * 64;
    const size_t actb = (size_t)b * NPIX * 64;
    for (int s = tid; s < 198; s += 256) {
        int r = s / 66, i = s % 66;
        int yy = y + r - 1, xx = x0 + i - 1;
        unsigned short* dst = &Bs[(r * 66 + i) * SP];
        if (yy >= 0 && yy < 192 && xx >= 0 && xx < 192) {
            const unsigned short* src = &act[actb + (size_t)(yy * 192 + xx) * 64];
            #pragma unroll
            for (int j = 0; j < 8; ++j) *(short8*)(dst + j * 8) = *(const short8*)(src + j * 8);
        } else {
            short8 z = {};
            #pragma unroll
            for (int j = 0; j < 8; ++j) *(short8*)(dst + j * 8) = z;
        }
    }
    __syncthreads();
    const int w = tid >> 6, l = tid & 63;
    const int ln = l & 15, lkg = l >> 4, lk = lkg * 8;
    const int mt = (MT == 4) ? w : 0;
    const int NT = (MT == 4) ? 4 : 1;
    const int ntb = (MT == 4) ? 0 : w;
    float4v acc[4] = {{0,0,0,0},{0,0,0,0},{0,0,0,0},{0,0,0,0}};
    #pragma unroll
    for (int t = 0; t < 9; ++t) {
        const int r = t / 3, dx = t % 3;
        #pragma unroll
        for (int ic0 = 0; ic0 < 64; ic0 += 32) {
            short8 a = *(const short8*)&wgt[((size_t)t * OCP + mt * 16 + ln) * 64 + ic0 + lk];
            #pragma unroll
            for (int n = 0; n < 4; ++n) {
                if (n >= NT) break;
                int slot = r * 66 + (ntb + n) * 16 + ln + dx;
                short8 bf = *(const short8*)&Bs[slot * SP + ic0 + lk];
                acc[n] = __builtin_amdgcn_mfma_f32_16x16x32_bf16(a, bf, acc[n], 0, 0, 0);
            }
        }
    }
    #pragma unroll
    for (int n = 0; n < 4; ++n) {
        if (n >= NT) break;
        int px = y * 192 + x0 + (ntb + n) * 16 + ln;
        if (MT == 4) {
            int oc = mt * 16 + lkg * 4;
            float v0 = acc[n][0] + bias[oc + 0];
            float v1 = acc[n][1] + bias[oc + 1];
            float v2 = acc[n][2] + bias[oc + 2];
            float v3 = acc[n][3] + bias[oc + 3];
            if (relu) { v0 = fmaxf(v0, 0.f); v1 = fmaxf(v1, 0.f); v2 = fmaxf(v2, 0.f); v3 = fmaxf(v3, 0.f); }
            uint2 pk;
            pk.x = (unsigned int)f2b(v0) | (((unsigned int)f2b(v1)) << 16);
            pk.y = (unsigned int)f2b(v2) | (((unsigned int)f2b(v3)) << 16);
            *(uint2*)&out[((size_t)b * NPIX + px) * ocw + oc] = pk;
        } else {
            if (lkg == 0) {   // oc = reg 0..3; keep 0,1
                float v0 = acc[n][0] + bias[0];
                float v1 = acc[n][1] + bias[1];
                unsigned int pk = (unsigned int)f2b(v0) | (((unsigned int)f2b(v1)) << 16);
                *(unsigned int*)&out[((size_t)b * NPIX + px) * 2] = pk;
            }
        }
    }
}

// ---------------------------------------------------------------- mean: thread-per-pixel over all 64 c
__global__ __launch_bounds__(256) void mean_k(
    const float* __restrict__ x, const int* __restrict__ imy, const int* __restrict__ imx,
    const unsigned short* __restrict__ dw, unsigned short* __restrict__ mean)
{
    int px = blockIdx.x * 256 + threadIdx.x;
    int b = blockIdx.y;
    int iy = imy[px], ix = imx[px];
    const float* xb = x + (size_t)b * 64 * 9216;
    const unsigned short* dr = dw + (size_t)px * 576;
    unsigned int pk[32];
    for (int c = 0; c < 64; ++c) {
        float d[9], h[9];
        const float* xp = xb + (size_t)c * 9216;
        #pragma unroll
        for (int k = 0; k < 9; ++k) {
            d[k] = b2f(dr[c * 9 + k]);
            int yy = iy + k / 3 - 1, xx = ix + k % 3 - 1;
            h[k] = (yy >= 0 && yy < 96 && xx >= 0 && xx < 96) ? xp[yy * 96 + xx] : 0.f;
        }
        float m = d[0];
        #pragma unroll
        for (int k = 1; k < 9; ++k) m = fmaxf(m, d[k]);
        float s = 0.f, a = 0.f;
        #pragma unroll
        for (int k = 0; k < 9; ++k) { float e = __expf(d[k] - m); s += e; a += e * h[k]; }
        unsigned short u = f2b(a / s);
        if (c & 1) pk[c >> 1] |= ((unsigned int)u) << 16; else pk[c >> 1] = u;
    }
    uint4* mo = (uint4*)&mean[((size_t)b * NPIX + px) * 64];
    #pragma unroll
    for (int q = 0; q < 8; ++q) mo[q] = ((uint4*)pk)[q];
}

// ---------------------------------------------------------------- xa + einsum fused
__global__ __launch_bounds__(256) void xa_k(
    const float* __restrict__ x, const int* __restrict__ imy, const int* __restrict__ imx,
    const unsigned short* __restrict__ dw, const unsigned short* __restrict__ mean,
    const unsigned short* __restrict__ sigma, const unsigned short* __restrict__ pw,
    float* __restrict__ out)
{
    int px = blockIdx.x * 256 + threadIdx.x;
    int b = blockIdx.y;
    int iy = imy[px], ix = imx[px];
    const float* xb = x + (size_t)b * 64 * 9216;
    const unsigned short* dr = dw + (size_t)px * 576;
    const unsigned short* mr = mean + ((size_t)b * NPIX + px) * 64;
    const unsigned short* pr = pw + (size_t)px * 192;
    float sd = b2f(sigma[((size_t)b * NPIX + px) * 2 + 0]);
    float sr = b2f(sigma[((size_t)b * NPIX + px) * 2 + 1]);
    float o0 = 0.f, o1 = 0.f, o2 = 0.f;
    for (int c = 0; c < 64; ++c) {
        float bw[9], h[9];
        float mn = b2f(mr[c]);
        const float* xp = xb + (size_t)c * 9216;
        #pragma unroll
        for (int k = 0; k < 9; ++k) {
            int yy = iy + k / 3 - 1, xx = ix + k % 3 - 1;
            h[k] = (yy >= 0 && yy < 96 && xx >= 0 && xx < 96) ? xp[yy * 96 + xx] : 0.f;
            float d = b2f(dr[c * 9 + k]);
            bw[k] = sd * d + sr * fabsf(h[k] - mn);
        }
        float m = bw[0];
        #pragma unroll
        for (int k = 1; k < 9; ++k) m = fmaxf(m, bw[k]);
        float s = 0.f, a = 0.f;
        #pragma unroll
        for (int k = 0; k < 9; ++k) { float e = __expf(bw[k] - m); s += e; a += e * h[k]; }
        float xac = a / s;
        o0 += xac * b2f(pr[c * 3 + 0]);
        o1 += xac * b2f(pr[c * 3 + 1]);
        o2 += xac * b2f(pr[c * 3 + 2]);
    }
    out[((size_t)b * 3 + 0) * NPIX + px] = o0;
    out[((size_t)b * 3 + 1) * NPIX + px] = o1;
    out[((size_t)b * 3 + 2) * NPIX + px] = o2;
}

extern "C" void kernel_launch(void* const* d_in, const int* in_sizes, int n_in,
                              void* d_out, int out_size, void* d_ws, size_t ws_size,
                              hipStream_t stream)
{
    (void)in_sizes; (void)n_in; (void)out_size; (void)ws_size;
    const float* x      = (const float*)d_in[0];
    const float* pose   = (const float*)d_in[1];
    const int*   imy    = (const int*)d_in[2];
    const int*   imx    = (const int*)d_in[3];
    const float* sig_w1 = (const float*)d_in[4];
    const float* sig_b1 = (const float*)d_in[5];
    const float* sig_w2 = (const float*)d_in[6];
    const float* sig_b2 = (const float*)d_in[7];
    const float* sig_w3 = (const float*)d_in[8];
    const float* sig_b3 = (const float*)d_in[9];
    const float* dw_w1  = (const float*)d_in[10];
    const float* dw_b1  = (const float*)d_in[11];
    const float* dw_w2  = (const float*)d_in[12];
    const float* dw_b2  = (const float*)d_in[13];
    const float* dw_w3  = (const float*)d_in[14];
    const float* dw_b3  = (const float*)d_in[15];
    const float* pw_w1  = (const float*)d_in[16];
    const float* pw_b1  = (const float*)d_in[17];
    const float* pw_w2  = (const float*)d_in[18];
    const float* pw_b2  = (const float*)d_in[19];
    const float* pw_w3  = (const float*)d_in[20];
    const float* pw_b3  = (const float*)d_in[21];
    float* out = (float*)d_out;

    unsigned short* ws = (unsigned short*)d_ws;
    size_t off = 0;
    unsigned short* wb    = ws + off; off += WB_TOTAL;                  // weights bf16
    unsigned short* h1    = ws + off; off += (size_t)NPIX * 64;
    unsigned short* h2    = ws + off; off += (size_t)NPIX * 256;
    unsigned short* dwbuf = ws + off; off += (size_t)NPIX * 576;
    unsigned short* pwbuf = ws + off; off += (size_t)NPIX * 192;
    unsigned short* meanb = ws + off; off += (size_t)2 * NPIX * 64;
    unsigned short* s1    = ws + off; off += (size_t)2 * NPIX * 64;
    unsigned short* s2    = ws + off; off += (size_t)2 * NPIX * 64;
    unsigned short* sigma = ws + off; off += (size_t)2 * NPIX * 2;

    unsigned short* w_dw2 = wb + 0;
    unsigned short* w_dw3 = wb + 16384;
    unsigned short* w_pw2 = wb + 163840;
    unsigned short* w_pw3 = wb + 180224;
    unsigned short* w_s1t = wb + 229376;
    unsigned short* w_s2t = wb + 266240;
    unsigned short* w_s3t = wb + 303104;

    dim3 blk(256);
    prep_w<<<dim3((WB_TOTAL + 255) / 256), blk, 0, stream>>>(dw_w2, dw_w3, pw_w2, pw_w3,
                                                             sig_w1, sig_w2, sig_w3, wb);
    // dw chain: 3 -> 64 -> 256 -> 576
    l1_k<<<dim3(144), blk, 0, stream>>>(pose, dw_w1, dw_b1, h1);
    gemm1x1<64 ><<<dim3(576, 4), blk, 0, stream>>>(h1, w_dw2, dw_b2, h2, 256, 1);
    gemm1x1<256><<<dim3(576, 9), blk, 0, stream>>>(h2, w_dw3, dw_b3, dwbuf, 576, 0);
    // pw chain: 3 -> 64 -> 256 -> 192
    l1_k<<<dim3(144), blk, 0, stream>>>(pose, pw_w1, pw_b1, h1);
    gemm1x1<64 ><<<dim3(576, 4), blk, 0, stream>>>(h1, w_pw2, pw_b2, h2, 256, 1);
    gemm1x1<256><<<dim3(576, 3), blk, 0, stream>>>(h2, w_pw3, pw_b3, pwbuf, 192, 0);
    // mean
    mean_k<<<dim3(144, 2), blk, 0, stream>>>(x, imy, imx, dwbuf, meanb);
    // sigma conv chain (3x3, pad 1): 64 -> 64 -> 64 -> 2(pad16)
    conv3x3_mfma<4><<<dim3(1152), blk, 0, stream>>>(meanb, w_s1t, sig_b1, s1, 64, 1);
    conv3x3_mfma<4><<<dim3(1152), blk, 0, stream>>>(s1,    w_s2t, sig_b2, s2, 64, 1);
    conv3x3_mfma<1><<<dim3(1152), blk, 0, stream>>>(s2,    w_s3t, sig_b3, sigma, 2, 0);
    // xa + einsum
    xa_k<<<dim3(144, 2), blk, 0, stream>>>(x, imy, imx, dwbuf, meanb, sigma, pwbuf, out);
}

// Round 3
// 461.635 us; speedup vs baseline: 2.3279x; 2.3279x over previous
//
#include <hip/hip_runtime.h>

#define NPIX 36864   // 192*192

typedef __attribute__((ext_vector_type(8))) short short8;
typedef __attribute__((ext_vector_type(4))) float float4v;

__device__ inline unsigned short f2b(float x) {
    unsigned int u = __float_as_uint(x);
    unsigned int r = (u + 0x7FFFu + ((u >> 16) & 1u)) >> 16;
    return (unsigned short)r;
}
__device__ inline float b2f(unsigned short h) {
    return __uint_as_float(((unsigned int)h) << 16);
}

// ---------------------------------------------------------------- weight prepass (bf16, MFMA layouts)
//  [0      ) dw_w2 [256][64]        n=16384
//  [16384  ) dw_w3 [576][256]       n=147456
//  [163840 ) pw_w2 [256][64]        n=16384
//  [180224 ) pw_w3 [192][256]       n=49152
//  [229376 ) sigW1t [9][64][64]     n=36864   (tap-major)
//  [266240 ) sigW2t [9][64][64]     n=36864
//  [303104 ) sigW3t [9][16][64]     n=9216    (oc padded 2->16 with zeros)
#define WB_TOTAL 312320
__global__ __launch_bounds__(256) void prep_w(
    const float* __restrict__ dw2, const float* __restrict__ dw3,
    const float* __restrict__ pw2, const float* __restrict__ pw3,
    const float* __restrict__ sw1, const float* __restrict__ sw2,
    const float* __restrict__ sw3, unsigned short* __restrict__ wb)
{
    int i = blockIdx.x * 256 + threadIdx.x;
    if (i >= WB_TOTAL) return;
    unsigned short v;
    if (i < 16384)        v = f2b(dw2[i]);
    else if (i < 163840)  v = f2b(dw3[i - 16384]);
    else if (i < 180224)  v = f2b(pw2[i - 163840]);
    else if (i < 229376)  v = f2b(pw3[i - 180224]);
    else if (i < 266240) { int j = i - 229376; int t = j / 4096, r = j % 4096, oc = r / 64, ic = r % 64;
                           v = f2b(sw1[(oc * 64 + ic) * 9 + t]); }
    else if (i < 303104) { int j = i - 266240; int t = j / 4096, r = j % 4096, oc = r / 64, ic = r % 64;
                           v = f2b(sw2[(oc * 64 + ic) * 9 + t]); }
    else                 { int j = i - 303104; int t = j / 1024, r = j % 1024, oc = r / 64, ic = r % 64;
                           v = (oc < 2) ? f2b(sw3[(oc * 64 + ic) * 9 + t]) : (unsigned short)0; }
    wb[i] = v;
}

// ---------------------------------------------------------------- x -> bf16 (same plane layout)
__global__ __launch_bounds__(256) void xcast_k(const float* __restrict__ x, unsigned short* __restrict__ xb)
{
    int i = blockIdx.x * 256 + threadIdx.x;   // 2*64*9216 = 1179648
    xb[i] = f2b(x[i]);
}

// ---------------------------------------------------------------- layer-1 1x1 (3 -> 64), out pixel-major bf16
__global__ __launch_bounds__(256) void l1_k(
    const float* __restrict__ pose, const float* __restrict__ w,
    const float* __restrict__ bias, unsigned short* __restrict__ out)
{
    int px = blockIdx.x * 256 + threadIdx.x;
    float p0 = pose[px], p1 = pose[NPIX + px], p2 = pose[2 * NPIX + px];
    unsigned int pk[32];
    #pragma unroll
    for (int c = 0; c < 64; ++c) {
        float v = bias[c] + w[c * 3] * p0 + w[c * 3 + 1] * p1 + w[c * 3 + 2] * p2;
        v = fmaxf(v, 0.f);
        unsigned short u = f2b(v);
        if (c & 1) pk[c >> 1] |= ((unsigned int)u) << 16; else pk[c >> 1] = u;
    }
    uint4* o = (uint4*)&out[(size_t)px * 64];
    #pragma unroll
    for (int q = 0; q < 8; ++q) o[q] = ((uint4*)pk)[q];
}

// ---------------------------------------------------------------- bf16 MFMA GEMM for 1x1 convs
// act: [NPIX][K] bf16 pixel-major, wgt: [OCtot][K] bf16.
// TR=0: out[px][octot] pixel-major. TR=1: out[oc][NPIX] plane-major.
template<int K, bool TR>
__global__ __launch_bounds__(256) void gemm1x1(
    const unsigned short* __restrict__ act, const unsigned short* __restrict__ wgt,
    const float* __restrict__ bias, unsigned short* __restrict__ out,
    int octot, int relu)
{
    constexpr int KP = K + 8;
    __shared__ unsigned short Bs[64 * KP];
    const int tid = threadIdx.x;
    const int px0 = blockIdx.x * 64;
    const int oc0 = blockIdx.y * 64;
    for (int idx = tid; idx < 64 * (K / 8); idx += 256) {
        int p = idx / (K / 8), ko = (idx % (K / 8)) * 8;
        *(short8*)&Bs[p * KP + ko] = *(const short8*)&act[(size_t)(px0 + p) * K + ko];
    }
    __syncthreads();
    const int w = tid >> 6, l = tid & 63;
    const int ln = l & 15, lkg = l >> 4, lk = lkg * 8;
    float4v acc[4] = {{0,0,0,0},{0,0,0,0},{0,0,0,0},{0,0,0,0}};
    const int ocA = oc0 + w * 16 + ln;
    #pragma unroll
    for (int kc = 0; kc < K; kc += 32) {
        short8 a = *(const short8*)&wgt[(size_t)ocA * K + kc + lk];
        #pragma unroll
        for (int nt = 0; nt < 4; ++nt) {
            short8 b = *(const short8*)&Bs[(nt * 16 + ln) * KP + kc + lk];
            acc[nt] = __builtin_amdgcn_mfma_f32_16x16x32_bf16(a, b, acc[nt], 0, 0, 0);
        }
    }
    #pragma unroll
    for (int nt = 0; nt < 4; ++nt) {
        int px = px0 + nt * 16 + ln;
        int oc = oc0 + w * 16 + lkg * 4;
        float v[4];
        #pragma unroll
        for (int r = 0; r < 4; ++r) {
            v[r] = acc[nt][r] + bias[oc + r];
            if (relu) v[r] = fmaxf(v[r], 0.f);
        }
        if (TR) {
            #pragma unroll
            for (int r = 0; r < 4; ++r)
                out[(size_t)(oc + r) * NPIX + px] = f2b(v[r]);
        } else {
            uint2 pk;
            pk.x = (unsigned int)f2b(v[0]) | (((unsigned int)f2b(v[1])) << 16);
            pk.y = (unsigned int)f2b(v[2]) | (((unsigned int)f2b(v[3])) << 16);
            *(uint2*)&out[(size_t)px * octot + oc] = pk;
        }
    }
}

// ---------------------------------------------------------------- bf16 MFMA 3x3 conv (implicit im2col)
// act: [B][NPIX][64] pixel-major; wgt: [9][OCP][64] tap-major.
// MT=4: out [B][NPIX][64] pixel-major. MT=1: out [B][2][NPIX] plane-major (oc<2).
template<int MT>
__global__ __launch_bounds__(256) void conv3x3_mfma(
    const unsigned short* __restrict__ act, const unsigned short* __restrict__ wgt,
    const float* __restrict__ bias, unsigned short* __restrict__ out,
    int relu)
{
    constexpr int SP = 72;
    constexpr int OCP = MT * 16;
    __shared__ unsigned short Bs[3 * 66 * SP];
    const int tid = threadIdx.x;
    int bx = blockIdx.x;
    const int xt = bx % 3; bx /= 3;
    const int y = bx % 192; const int b = bx / 192;
    const int x0 = xt * 64;
    const size_t actb = (size_t)b * NPIX * 64;
    for (int s = tid; s < 198; s += 256) {
        int r = s / 66, i = s % 66;
        int yy = y + r - 1, xx = x0 + i - 1;
        unsigned short* dst = &Bs[(r * 66 + i) * SP];
        if (yy >= 0 && yy < 192 && xx >= 0 && xx < 192) {
            const unsigned short* src = &act[actb + (size_t)(yy * 192 + xx) * 64];
            #pragma unroll
            for (int j = 0; j < 8; ++j) *(short8*)(dst + j * 8) = *(const short8*)(src + j * 8);
        } else {
            short8 z = {};
            #pragma unroll
            for (int j = 0; j < 8; ++j) *(short8*)(dst + j * 8) = z;
        }
    }
    __syncthreads();
    const int w = tid >> 6, l = tid & 63;
    const int ln = l & 15, lkg = l >> 4, lk = lkg * 8;
    const int mt = (MT == 4) ? w : 0;
    const int NT = (MT == 4) ? 4 : 1;
    const int ntb = (MT == 4) ? 0 : w;
    float4v acc[4] = {{0,0,0,0},{0,0,0,0},{0,0,0,0},{0,0,0,0}};
    #pragma unroll
    for (int t = 0; t < 9; ++t) {
        const int r = t / 3, dx = t % 3;
        #pragma unroll
        for (int ic0 = 0; ic0 < 64; ic0 += 32) {
            short8 a = *(const short8*)&wgt[((size_t)t * OCP + mt * 16 + ln) * 64 + ic0 + lk];
            #pragma unroll
            for (int n = 0; n < 4; ++n) {
                if (n >= NT) break;
                int slot = r * 66 + (ntb + n) * 16 + ln + dx;
                short8 bf = *(const short8*)&Bs[slot * SP + ic0 + lk];
                acc[n] = __builtin_amdgcn_mfma_f32_16x16x32_bf16(a, bf, acc[n], 0, 0, 0);
            }
        }
    }
    #pragma unroll
    for (int n = 0; n < 4; ++n) {
        if (n >= NT) break;
        int px = y * 192 + x0 + (ntb + n) * 16 + ln;
        if (MT == 4) {
            int oc = mt * 16 + lkg * 4;
            float v0 = acc[n][0] + bias[oc + 0];
            float v1 = acc[n][1] + bias[oc + 1];
            float v2 = acc[n][2] + bias[oc + 2];
            float v3 = acc[n][3] + bias[oc + 3];
            if (relu) { v0 = fmaxf(v0, 0.f); v1 = fmaxf(v1, 0.f); v2 = fmaxf(v2, 0.f); v3 = fmaxf(v3, 0.f); }
            uint2 pk;
            pk.x = (unsigned int)f2b(v0) | (((unsigned int)f2b(v1)) << 16);
            pk.y = (unsigned int)f2b(v2) | (((unsigned int)f2b(v3)) << 16);
            *(uint2*)&out[((size_t)b * NPIX + px) * 64 + oc] = pk;
        } else if (lkg == 0) {
            float v0 = acc[n][0] + bias[0];
            float v1 = acc[n][1] + bias[1];
            out[((size_t)b * 2 + 0) * NPIX + px] = f2b(v0);
            out[((size_t)b * 2 + 1) * NPIX + px] = f2b(v1);
        }
    }
}

// ---------------------------------------------------------------- mean: block per c, both b in-loop
// dw: [576][NPIX] plane-major bf16; xb: [2][64][9216] bf16; mean_cm: [2][64][NPIX] bf16
__global__ __launch_bounds__(256) void mean_k(
    const unsigned short* __restrict__ xb, const int* __restrict__ imy, const int* __restrict__ imx,
    const unsigned short* __restrict__ dw, unsigned short* __restrict__ mean_cm)
{
    int px = blockIdx.x * 256 + threadIdx.x;
    int c = blockIdx.y;
    int iy = imy[px], ix = imx[px];
    float wk[9];
    {
        float d[9];
        #pragma unroll
        for (int k = 0; k < 9; ++k) d[k] = b2f(dw[(size_t)(c * 9 + k) * NPIX + px]);
        float m = d[0];
        #pragma unroll
        for (int k = 1; k < 9; ++k) m = fmaxf(m, d[k]);
        float s = 0.f;
        #pragma unroll
        for (int k = 0; k < 9; ++k) { wk[k] = __expf(d[k] - m); s += wk[k]; }
        float inv = 1.f / s;
        #pragma unroll
        for (int k = 0; k < 9; ++k) wk[k] *= inv;
    }
    #pragma unroll
    for (int b = 0; b < 2; ++b) {
        const unsigned short* xp = xb + (size_t)(b * 64 + c) * 9216;
        float a = 0.f;
        #pragma unroll
        for (int k = 0; k < 9; ++k) {
            int yy = iy + k / 3 - 1, xx = ix + k % 3 - 1;
            float h = (yy >= 0 && yy < 96 && xx >= 0 && xx < 96) ? b2f(xp[yy * 96 + xx]) : 0.f;
            a += wk[k] * h;
        }
        mean_cm[(size_t)(b * 64 + c) * NPIX + px] = f2b(a);
    }
}

// ---------------------------------------------------------------- transpose [2][64][NPIX] -> [2][NPIX][64]
__global__ __launch_bounds__(256) void tr_k(
    const unsigned short* __restrict__ in, unsigned short* __restrict__ out)
{
    __shared__ unsigned short T[64 * 68];
    int px0 = blockIdx.x * 64;
    int b = blockIdx.y;
    int tid = threadIdx.x;
    for (int i = tid; i < 4096; i += 256) {
        int c = i >> 6, p = i & 63;
        T[p * 68 + c] = in[(size_t)(b * 64 + c) * NPIX + px0 + p];
    }
    __syncthreads();
    for (int i = tid; i < 4096; i += 256) {
        int p = i >> 6, c = i & 63;
        out[((size_t)b * NPIX + px0 + p) * 64 + c] = T[p * 68 + c];
    }
}

// ---------------------------------------------------------------- xa: block per c, both b in-loop
__global__ __launch_bounds__(256) void xa_k(
    const unsigned short* __restrict__ xb, const int* __restrict__ imy, const int* __restrict__ imx,
    const unsigned short* __restrict__ dw, const unsigned short* __restrict__ mean_cm,
    const unsigned short* __restrict__ sigma, unsigned short* __restrict__ xab)
{
    int px = blockIdx.x * 256 + threadIdx.x;
    int c = blockIdx.y;
    int iy = imy[px], ix = imx[px];
    float d[9];
    #pragma unroll
    for (int k = 0; k < 9; ++k) d[k] = b2f(dw[(size_t)(c * 9 + k) * NPIX + px]);
    #pragma unroll
    for (int b = 0; b < 2; ++b) {
        const unsigned short* xp = xb + (size_t)(b * 64 + c) * 9216;
        float mn = b2f(mean_cm[(size_t)(b * 64 + c) * NPIX + px]);
        float sd = b2f(sigma[((size_t)b * 2 + 0) * NPIX + px]);
        float sr = b2f(sigma[((size_t)b * 2 + 1) * NPIX + px]);
        float h[9], bw[9];
        #pragma unroll
        for (int k = 0; k < 9; ++k) {
            int yy = iy + k / 3 - 1, xx = ix + k % 3 - 1;
            h[k] = (yy >= 0 && yy < 96 && xx >= 0 && xx < 96) ? b2f(xp[yy * 96 + xx]) : 0.f;
            bw[k] = sd * d[k] + sr * fabsf(h[k] - mn);
        }
        float m = bw[0];
        #pragma unroll
        for (int k = 1; k < 9; ++k) m = fmaxf(m, bw[k]);
        float s = 0.f, a = 0.f;
        #pragma unroll
        for (int k = 0; k < 9; ++k) { float e = __expf(bw[k] - m); s += e; a += e * h[k]; }
        xab[(size_t)(b * 64 + c) * NPIX + px] = f2b(a / s);
    }
}

// ---------------------------------------------------------------- out[b,o,px] = sum_c xa[b,c,px]*pw[c,o,px]
__global__ __launch_bounds__(256) void einsum_k(
    const unsigned short* __restrict__ xab, const unsigned short* __restrict__ pw,
    float* __restrict__ out)
{
    int px = blockIdx.x * 256 + threadIdx.x;
    int b = blockIdx.y;
    float a0 = 0.f, a1 = 0.f, a2 = 0.f;
    for (int c = 0; c < 64; ++c) {
        float v = b2f(xab[(size_t)(b * 64 + c) * NPIX + px]);
        a0 += v * b2f(pw[(size_t)(c * 3 + 0) * NPIX + px]);
        a1 += v * b2f(pw[(size_t)(c * 3 + 1) * NPIX + px]);
        a2 += v * b2f(pw[(size_t)(c * 3 + 2) * NPIX + px]);
    }
    out[((size_t)b * 3 + 0) * NPIX + px] = a0;
    out[((size_t)b * 3 + 1) * NPIX + px] = a1;
    out[((size_t)b * 3 + 2) * NPIX + px] = a2;
}

extern "C" void kernel_launch(void* const* d_in, const int* in_sizes, int n_in,
                              void* d_out, int out_size, void* d_ws, size_t ws_size,
                              hipStream_t stream)
{
    (void)in_sizes; (void)n_in; (void)out_size; (void)ws_size;
    const float* x      = (const float*)d_in[0];
    const float* pose   = (const float*)d_in[1];
    const int*   imy    = (const int*)d_in[2];
    const int*   imx    = (const int*)d_in[3];
    const float* sig_w1 = (const float*)d_in[4];
    const float* sig_b1 = (const float*)d_in[5];
    const float* sig_w2 = (const float*)d_in[6];
    const float* sig_b2 = (const float*)d_in[7];
    const float* sig_w3 = (const float*)d_in[8];
    const float* sig_b3 = (const float*)d_in[9];
    const float* dw_w1  = (const float*)d_in[10];
    const float* dw_b1  = (const float*)d_in[11];
    const float* dw_w2  = (const float*)d_in[12];
    const float* dw_b2  = (const float*)d_in[13];
    const float* dw_w3  = (const float*)d_in[14];
    const float* dw_b3  = (const float*)d_in[15];
    const float* pw_w1  = (const float*)d_in[16];
    const float* pw_b1  = (const float*)d_in[17];
    const float* pw_w2  = (const float*)d_in[18];
    const float* pw_b2  = (const float*)d_in[19];
    const float* pw_w3  = (const float*)d_in[20];
    const float* pw_b3  = (const float*)d_in[21];
    float* out = (float*)d_out;

    unsigned short* ws = (unsigned short*)d_ws;
    size_t off = 0;
    unsigned short* wb      = ws + off; off += WB_TOTAL;
    unsigned short* xb16    = ws + off; off += (size_t)2 * 64 * 9216;
    unsigned short* h1      = ws + off; off += (size_t)NPIX * 64;
    unsigned short* h2      = ws + off; off += (size_t)NPIX * 256;
    unsigned short* dwbuf   = ws + off; off += (size_t)576 * NPIX;    // plane-major
    unsigned short* pwbuf   = ws + off; off += (size_t)192 * NPIX;    // plane-major
    unsigned short* mean_cm = ws + off; off += (size_t)2 * 64 * NPIX; // plane-major
    unsigned short* mean_pm = ws + off; off += (size_t)2 * NPIX * 64; // pixel-major
    unsigned short* s1      = ws + off; off += (size_t)2 * NPIX * 64;
    unsigned short* s2      = ws + off; off += (size_t)2 * NPIX * 64;
    unsigned short* sigma   = ws + off; off += (size_t)2 * 2 * NPIX;  // plane-major
    unsigned short* xab     = ws + off; off += (size_t)2 * 64 * NPIX; // plane-major

    unsigned short* w_dw2 = wb + 0;
    unsigned short* w_dw3 = wb + 16384;
    unsigned short* w_pw2 = wb + 163840;
    unsigned short* w_pw3 = wb + 180224;
    unsigned short* w_s1t = wb + 229376;
    unsigned short* w_s2t = wb + 266240;
    unsigned short* w_s3t = wb + 303104;

    dim3 blk(256);
    prep_w<<<dim3((WB_TOTAL + 255) / 256), blk, 0, stream>>>(dw_w2, dw_w3, pw_w2, pw_w3,
                                                             sig_w1, sig_w2, sig_w3, wb);
    xcast_k<<<dim3(4608), blk, 0, stream>>>(x, xb16);
    // dw chain: 3 -> 64 -> 256 -> 576 (576 stored plane-major)
    l1_k<<<dim3(144), blk, 0, stream>>>(pose, dw_w1, dw_b1, h1);
    gemm1x1<64,  false><<<dim3(576, 4), blk, 0, stream>>>(h1, w_dw2, dw_b2, h2, 256, 1);
    gemm1x1<256, true ><<<dim3(576, 9), blk, 0, stream>>>(h2, w_dw3, dw_b3, dwbuf, 576, 0);
    // pw chain: 3 -> 64 -> 256 -> 192 (192 stored plane-major)
    l1_k<<<dim3(144), blk, 0, stream>>>(pose, pw_w1, pw_b1, h1);
    gemm1x1<64,  false><<<dim3(576, 4), blk, 0, stream>>>(h1, w_pw2, pw_b2, h2, 256, 1);
    gemm1x1<256, true ><<<dim3(576, 3), blk, 0, stream>>>(h2, w_pw3, pw_b3, pwbuf, 192, 0);
    // mean (plane-major) + transpose to pixel-major for conv chain
    mean_k<<<dim3(144, 64), blk, 0, stream>>>(xb16, imy, imx, dwbuf, mean_cm);
    tr_k<<<dim3(576, 2), blk, 0, stream>>>(mean_cm, mean_pm);
    // sigma conv chain (3x3, pad 1): 64 -> 64 -> 64 -> 2 (plane-major)
    conv3x3_mfma<4><<<dim3(1152), blk, 0, stream>>>(mean_pm, w_s1t, sig_b1, s1, 1);
    conv3x3_mfma<4><<<dim3(1152), blk, 0, stream>>>(s1,      w_s2t, sig_b2, s2, 1);
    conv3x3_mfma<1><<<dim3(1152), blk, 0, stream>>>(s2,      w_s3t, sig_b3, sigma, 0);
    // xa (plane-major), then einsum
    xa_k<<<dim3(144, 64), blk, 0, stream>>>(xb16, imy, imx, dwbuf, mean_cm, sigma, xab);
    einsum_k<<<dim3(144, 2), blk, 0, stream>>>(xab, pwbuf, out);
}

// Round 4
// 297.441 us; speedup vs baseline: 3.6130x; 1.5520x over previous
//
#include <hip/hip_runtime.h>

#define NPIX 36864   // 192*192

typedef __attribute__((ext_vector_type(8))) short short8;
typedef __attribute__((ext_vector_type(4))) float float4v;

__device__ inline unsigned short f2b(float x) {
    unsigned int u = __float_as_uint(x);
    unsigned int r = (u + 0x7FFFu + ((u >> 16) & 1u)) >> 16;
    return (unsigned short)r;
}
__device__ inline float b2f(unsigned short h) {
    return __uint_as_float(((unsigned int)h) << 16);
}

// ---------------------------------------------------------------- weight prepass (bf16, MFMA layouts)
#define WB_TOTAL 312320
__global__ __launch_bounds__(256) void prep_w(
    const float* __restrict__ dw2, const float* __restrict__ dw3,
    const float* __restrict__ pw2, const float* __restrict__ pw3,
    const float* __restrict__ sw1, const float* __restrict__ sw2,
    const float* __restrict__ sw3, unsigned short* __restrict__ wb)
{
    int i = blockIdx.x * 256 + threadIdx.x;
    if (i >= WB_TOTAL) return;
    unsigned short v;
    if (i < 16384)        v = f2b(dw2[i]);
    else if (i < 163840)  v = f2b(dw3[i - 16384]);
    else if (i < 180224)  v = f2b(pw2[i - 163840]);
    else if (i < 229376)  v = f2b(pw3[i - 180224]);
    else if (i < 266240) { int j = i - 229376; int t = j / 4096, r = j % 4096, oc = r / 64, ic = r % 64;
                           v = f2b(sw1[(oc * 64 + ic) * 9 + t]); }
    else if (i < 303104) { int j = i - 266240; int t = j / 4096, r = j % 4096, oc = r / 64, ic = r % 64;
                           v = f2b(sw2[(oc * 64 + ic) * 9 + t]); }
    else                 { int j = i - 303104; int t = j / 1024, r = j % 1024, oc = r / 64, ic = r % 64;
                           v = (oc < 2) ? f2b(sw3[(oc * 64 + ic) * 9 + t]) : (unsigned short)0; }
    wb[i] = v;
}

// ---------------------------------------------------------------- x -> bf16
__global__ __launch_bounds__(256) void xcast_k(const float* __restrict__ x, unsigned short* __restrict__ xb)
{
    int i = blockIdx.x * 256 + threadIdx.x;
    xb[i] = f2b(x[i]);
}

// ---------------------------------------------------------------- layer-1 1x1 (3 -> 64)
__global__ __launch_bounds__(256) void l1_k(
    const float* __restrict__ pose, const float* __restrict__ w,
    const float* __restrict__ bias, unsigned short* __restrict__ out)
{
    int px = blockIdx.x * 256 + threadIdx.x;
    float p0 = pose[px], p1 = pose[NPIX + px], p2 = pose[2 * NPIX + px];
    unsigned int pk[32];
    #pragma unroll
    for (int c = 0; c < 64; ++c) {
        float v = bias[c] + w[c * 3] * p0 + w[c * 3 + 1] * p1 + w[c * 3 + 2] * p2;
        v = fmaxf(v, 0.f);
        unsigned short u = f2b(v);
        if (c & 1) pk[c >> 1] |= ((unsigned int)u) << 16; else pk[c >> 1] = u;
    }
    uint4* o = (uint4*)&out[(size_t)px * 64];
    #pragma unroll
    for (int q = 0; q < 8; ++q) o[q] = ((uint4*)pk)[q];
}

// ---------------------------------------------------------------- bf16 MFMA GEMM (1x1 convs)
template<int K, bool TR>
__global__ __launch_bounds__(256) void gemm1x1(
    const unsigned short* __restrict__ act, const unsigned short* __restrict__ wgt,
    const float* __restrict__ bias, unsigned short* __restrict__ out,
    int octot, int relu)
{
    constexpr int KP = K + 8;
    __shared__ unsigned short Bs[64 * KP];
    const int tid = threadIdx.x;
    const int px0 = blockIdx.x * 64;
    const int oc0 = blockIdx.y * 64;
    for (int idx = tid; idx < 64 * (K / 8); idx += 256) {
        int p = idx / (K / 8), ko = (idx % (K / 8)) * 8;
        *(short8*)&Bs[p * KP + ko] = *(const short8*)&act[(size_t)(px0 + p) * K + ko];
    }
    __syncthreads();
    const int w = tid >> 6, l = tid & 63;
    const int ln = l & 15, lkg = l >> 4, lk = lkg * 8;
    float4v acc[4] = {{0,0,0,0},{0,0,0,0},{0,0,0,0},{0,0,0,0}};
    const int ocA = oc0 + w * 16 + ln;
    #pragma unroll
    for (int kc = 0; kc < K; kc += 32) {
        short8 a = *(const short8*)&wgt[(size_t)ocA * K + kc + lk];
        #pragma unroll
        for (int nt = 0; nt < 4; ++nt) {
            short8 b = *(const short8*)&Bs[(nt * 16 + ln) * KP + kc + lk];
            acc[nt] = __builtin_amdgcn_mfma_f32_16x16x32_bf16(a, b, acc[nt], 0, 0, 0);
        }
    }
    #pragma unroll
    for (int nt = 0; nt < 4; ++nt) {
        int px = px0 + nt * 16 + ln;
        int oc = oc0 + w * 16 + lkg * 4;
        float v[4];
        #pragma unroll
        for (int r = 0; r < 4; ++r) {
            v[r] = acc[nt][r] + bias[oc + r];
            if (relu) v[r] = fmaxf(v[r], 0.f);
        }
        if (TR) {
            #pragma unroll
            for (int r = 0; r < 4; ++r)
                out[(size_t)(oc + r) * NPIX + px] = f2b(v[r]);
        } else {
            uint2 pk;
            pk.x = (unsigned int)f2b(v[0]) | (((unsigned int)f2b(v[1])) << 16);
            pk.y = (unsigned int)f2b(v[2]) | (((unsigned int)f2b(v[3])) << 16);
            *(uint2*)&out[(size_t)px * octot + oc] = pk;
        }
    }
}

// ---------------------------------------------------------------- bf16 MFMA 3x3 conv
template<int MT>
__global__ __launch_bounds__(256) void conv3x3_mfma(
    const unsigned short* __restrict__ act, const unsigned short* __restrict__ wgt,
    const float* __restrict__ bias, unsigned short* __restrict__ out,
    int relu)
{
    constexpr int SP = 72;
    constexpr int OCP = MT * 16;
    __shared__ unsigned short Bs[3 * 66 * SP];
    const int tid = threadIdx.x;
    int bx = blockIdx.x;
    const int xt = bx % 3; bx /= 3;
    const int y = bx % 192; const int b = bx / 192;
    const int x0 = xt * 64;
    const size_t actb = (size_t)b * NPIX * 64;
    for (int s = tid; s < 198; s += 256) {
        int r = s / 66, i = s % 66;
        int yy = y + r - 1, xx = x0 + i - 1;
        unsigned short* dst = &Bs[(r * 66 + i) * SP];
        if (yy >= 0 && yy < 192 && xx >= 0 && xx < 192) {
            const unsigned short* src = &act[actb + (size_t)(yy * 192 + xx) * 64];
            #pragma unroll
            for (int j = 0; j < 8; ++j) *(short8*)(dst + j * 8) = *(const short8*)(src + j * 8);
        } else {
            short8 z = {};
            #pragma unroll
            for (int j = 0; j < 8; ++j) *(short8*)(dst + j * 8) = z;
        }
    }
    __syncthreads();
    const int w = tid >> 6, l = tid & 63;
    const int ln = l & 15, lkg = l >> 4, lk = lkg * 8;
    const int mt = (MT == 4) ? w : 0;
    const int NT = (MT == 4) ? 4 : 1;
    const int ntb = (MT == 4) ? 0 : w;
    float4v acc[4] = {{0,0,0,0},{0,0,0,0},{0,0,0,0},{0,0,0,0}};
    #pragma unroll
    for (int t = 0; t < 9; ++t) {
        const int r = t / 3, dx = t % 3;
        #pragma unroll
        for (int ic0 = 0; ic0 < 64; ic0 += 32) {
            short8 a = *(const short8*)&wgt[((size_t)t * OCP + mt * 16 + ln) * 64 + ic0 + lk];
            #pragma unroll
            for (int n = 0; n < 4; ++n) {
                if (n >= NT) break;
                int slot = r * 66 + (ntb + n) * 16 + ln + dx;
                short8 bf = *(const short8*)&Bs[slot * SP + ic0 + lk];
                acc[n] = __builtin_amdgcn_mfma_f32_16x16x32_bf16(a, bf, acc[n], 0, 0, 0);
            }
        }
    }
    #pragma unroll
    for (int n = 0; n < 4; ++n) {
        if (n >= NT) break;
        int px = y * 192 + x0 + (ntb + n) * 16 + ln;
        if (MT == 4) {
            int oc = mt * 16 + lkg * 4;
            float v0 = acc[n][0] + bias[oc + 0];
            float v1 = acc[n][1] + bias[oc + 1];
            float v2 = acc[n][2] + bias[oc + 2];
            float v3 = acc[n][3] + bias[oc + 3];
            if (relu) { v0 = fmaxf(v0, 0.f); v1 = fmaxf(v1, 0.f); v2 = fmaxf(v2, 0.f); v3 = fmaxf(v3, 0.f); }
            uint2 pk;
            pk.x = (unsigned int)f2b(v0) | (((unsigned int)f2b(v1)) << 16);
            pk.y = (unsigned int)f2b(v2) | (((unsigned int)f2b(v3)) << 16);
            *(uint2*)&out[((size_t)b * NPIX + px) * 64 + oc] = pk;
        } else if (lkg == 0) {
            float v0 = acc[n][0] + bias[0];
            float v1 = acc[n][1] + bias[1];
            out[((size_t)b * 2 + 0) * NPIX + px] = f2b(v0);
            out[((size_t)b * 2 + 1) * NPIX + px] = f2b(v1);
        }
    }
}

// ---------------------------------------------------------------- mean: LDS-resident plane gather
// block = (1024 px, c); LDS holds both b-planes of channel c (36 KB)
__global__ __launch_bounds__(256) void mean_k(
    const unsigned short* __restrict__ xb, const int* __restrict__ imy, const int* __restrict__ imx,
    const unsigned short* __restrict__ dw, unsigned short* __restrict__ mean_cm)
{
    __shared__ unsigned short pl[2][9216];
    const int c = blockIdx.y;
    const int px0 = blockIdx.x * 1024;
    const int tid = threadIdx.x;
    {
        const short8* s0 = (const short8*)(xb + (size_t)c * 9216);
        const short8* s1 = (const short8*)(xb + (size_t)(64 + c) * 9216);
        short8* d0 = (short8*)pl[0];
        short8* d1 = (short8*)pl[1];
        for (int i = tid; i < 1152; i += 256) { d0[i] = s0[i]; d1[i] = s1[i]; }
    }
    __syncthreads();
    #pragma unroll
    for (int q = 0; q < 4; ++q) {
        int px = px0 + q * 256 + tid;
        int iy = imy[px], ix = imx[px];
        float wk[9];
        {
            float d[9];
            #pragma unroll
            for (int k = 0; k < 9; ++k) d[k] = b2f(dw[(size_t)(c * 9 + k) * NPIX + px]);
            float m = d[0];
            #pragma unroll
            for (int k = 1; k < 9; ++k) m = fmaxf(m, d[k]);
            float s = 0.f;
            #pragma unroll
            for (int k = 0; k < 9; ++k) { wk[k] = __expf(d[k] - m); s += wk[k]; }
            float inv = 1.f / s;
            #pragma unroll
            for (int k = 0; k < 9; ++k) wk[k] *= inv;
        }
        #pragma unroll
        for (int b = 0; b < 2; ++b) {
            float a = 0.f;
            #pragma unroll
            for (int k = 0; k < 9; ++k) {
                int yy = iy + k / 3 - 1, xx = ix + k % 3 - 1;
                float h = (yy >= 0 && yy < 96 && xx >= 0 && xx < 96) ? b2f(pl[b][yy * 96 + xx]) : 0.f;
                a += wk[k] * h;
            }
            mean_cm[(size_t)(b * 64 + c) * NPIX + px] = f2b(a);
        }
    }
}

// ---------------------------------------------------------------- transpose [2][64][NPIX] -> [2][NPIX][64]
__global__ __launch_bounds__(256) void tr_k(
    const unsigned short* __restrict__ in, unsigned short* __restrict__ out)
{
    __shared__ unsigned short T[64 * 68];
    int px0 = blockIdx.x * 64;
    int b = blockIdx.y;
    int tid = threadIdx.x;
    for (int i = tid; i < 4096; i += 256) {
        int c = i >> 6, p = i & 63;
        T[p * 68 + c] = in[(size_t)(b * 64 + c) * NPIX + px0 + p];
    }
    __syncthreads();
    for (int i = tid; i < 4096; i += 256) {
        int p = i >> 6, c = i & 63;
        out[((size_t)b * NPIX + px0 + p) * 64 + c] = T[p * 68 + c];
    }
}

// ---------------------------------------------------------------- xa: LDS-resident plane gather
__global__ __launch_bounds__(256) void xa_k(
    const unsigned short* __restrict__ xb, const int* __restrict__ imy, const int* __restrict__ imx,
    const unsigned short* __restrict__ dw, const unsigned short* __restrict__ mean_cm,
    const unsigned short* __restrict__ sigma, unsigned short* __restrict__ xab)
{
    __shared__ unsigned short pl[2][9216];
    const int c = blockIdx.y;
    const int px0 = blockIdx.x * 1024;
    const int tid = threadIdx.x;
    {
        const short8* s0 = (const short8*)(xb + (size_t)c * 9216);
        const short8* s1 = (const short8*)(xb + (size_t)(64 + c) * 9216);
        short8* d0 = (short8*)pl[0];
        short8* d1 = (short8*)pl[1];
        for (int i = tid; i < 1152; i += 256) { d0[i] = s0[i]; d1[i] = s1[i]; }
    }
    __syncthreads();
    #pragma unroll
    for (int q = 0; q < 4; ++q) {
        int px = px0 + q * 256 + tid;
        int iy = imy[px], ix = imx[px];
        float d[9];
        #pragma unroll
        for (int k = 0; k < 9; ++k) d[k] = b2f(dw[(size_t)(c * 9 + k) * NPIX + px]);
        #pragma unroll
        for (int b = 0; b < 2; ++b) {
            float mn = b2f(mean_cm[(size_t)(b * 64 + c) * NPIX + px]);
            float sd = b2f(sigma[((size_t)b * 2 + 0) * NPIX + px]);
            float sr = b2f(sigma[((size_t)b * 2 + 1) * NPIX + px]);
            float h[9], bw[9];
            #pragma unroll
            for (int k = 0; k < 9; ++k) {
                int yy = iy + k / 3 - 1, xx = ix + k % 3 - 1;
                h[k] = (yy >= 0 && yy < 96 && xx >= 0 && xx < 96) ? b2f(pl[b][yy * 96 + xx]) : 0.f;
                bw[k] = sd * d[k] + sr * fabsf(h[k] - mn);
            }
            float m = bw[0];
            #pragma unroll
            for (int k = 1; k < 9; ++k) m = fmaxf(m, bw[k]);
            float s = 0.f, a = 0.f;
            #pragma unroll
            for (int k = 0; k < 9; ++k) { float e = __expf(bw[k] - m); s += e; a += e * h[k]; }
            xab[(size_t)(b * 64 + c) * NPIX + px] = f2b(a / s);
        }
    }
}

// ---------------------------------------------------------------- einsum partials over 16-c chunks
__global__ __launch_bounds__(256) void einsum_part(
    const unsigned short* __restrict__ xab, const unsigned short* __restrict__ pw,
    float* __restrict__ part)
{
    int px = blockIdx.x * 256 + threadIdx.x;
    int b = blockIdx.y;
    int c0 = blockIdx.z * 16;
    float a0 = 0.f, a1 = 0.f, a2 = 0.f;
    #pragma unroll
    for (int c = 0; c < 16; ++c) {
        float v = b2f(xab[(size_t)(b * 64 + c0 + c) * NPIX + px]);
        a0 += v * b2f(pw[(size_t)((c0 + c) * 3 + 0) * NPIX + px]);
        a1 += v * b2f(pw[(size_t)((c0 + c) * 3 + 1) * NPIX + px]);
        a2 += v * b2f(pw[(size_t)((c0 + c) * 3 + 2) * NPIX + px]);
    }
    size_t base = ((size_t)blockIdx.z * 6 + b * 3) * NPIX + px;
    part[base + 0 * NPIX] = a0;
    part[base + 1 * NPIX] = a1;
    part[base + 2 * NPIX] = a2;
}

__global__ __launch_bounds__(256) void einsum_red(
    const float* __restrict__ part, float* __restrict__ out)
{
    int i = blockIdx.x * 256 + threadIdx.x;   // over 6*NPIX
    float s = part[i] + part[(size_t)6 * NPIX + i] + part[(size_t)12 * NPIX + i] + part[(size_t)18 * NPIX + i];
    out[i] = s;
}

extern "C" void kernel_launch(void* const* d_in, const int* in_sizes, int n_in,
                              void* d_out, int out_size, void* d_ws, size_t ws_size,
                              hipStream_t stream)
{
    (void)in_sizes; (void)n_in; (void)out_size; (void)ws_size;
    const float* x      = (const float*)d_in[0];
    const float* pose   = (const float*)d_in[1];
    const int*   imy    = (const int*)d_in[2];
    const int*   imx    = (const int*)d_in[3];
    const float* sig_w1 = (const float*)d_in[4];
    const float* sig_b1 = (const float*)d_in[5];
    const float* sig_w2 = (const float*)d_in[6];
    const float* sig_b2 = (const float*)d_in[7];
    const float* sig_w3 = (const float*)d_in[8];
    const float* sig_b3 = (const float*)d_in[9];
    const float* dw_w1  = (const float*)d_in[10];
    const float* dw_b1  = (const float*)d_in[11];
    const float* dw_w2  = (const float*)d_in[12];
    const float* dw_b2  = (const float*)d_in[13];
    const float* dw_w3  = (const float*)d_in[14];
    const float* dw_b3  = (const float*)d_in[15];
    const float* pw_w1  = (const float*)d_in[16];
    const float* pw_b1  = (const float*)d_in[17];
    const float* pw_w2  = (const float*)d_in[18];
    const float* pw_b2  = (const float*)d_in[19];
    const float* pw_w3  = (const float*)d_in[20];
    const float* pw_b3  = (const float*)d_in[21];
    float* out = (float*)d_out;

    unsigned short* ws = (unsigned short*)d_ws;
    size_t off = 0;
    unsigned short* wb      = ws + off; off += WB_TOTAL;
    unsigned short* xb16    = ws + off; off += (size_t)2 * 64 * 9216;
    unsigned short* h1      = ws + off; off += (size_t)NPIX * 64;
    unsigned short* h2      = ws + off; off += (size_t)NPIX * 256;
    unsigned short* dwbuf   = ws + off; off += (size_t)576 * NPIX;    // plane-major
    unsigned short* pwbuf   = ws + off; off += (size_t)192 * NPIX;    // plane-major
    unsigned short* mean_cm = ws + off; off += (size_t)2 * 64 * NPIX;
    unsigned short* mean_pm = ws + off; off += (size_t)2 * NPIX * 64;
    unsigned short* s1      = ws + off; off += (size_t)2 * NPIX * 64;
    unsigned short* s2      = ws + off; off += (size_t)2 * NPIX * 64;
    unsigned short* sigma   = ws + off; off += (size_t)2 * 2 * NPIX;
    unsigned short* xab     = ws + off; off += (size_t)2 * 64 * NPIX;
    off = (off + 1) & ~(size_t)1;
    float* part = (float*)(ws + off);  // 4*6*NPIX floats

    unsigned short* w_dw2 = wb + 0;
    unsigned short* w_dw3 = wb + 16384;
    unsigned short* w_pw2 = wb + 163840;
    unsigned short* w_pw3 = wb + 180224;
    unsigned short* w_s1t = wb + 229376;
    unsigned short* w_s2t = wb + 266240;
    unsigned short* w_s3t = wb + 303104;

    dim3 blk(256);
    prep_w<<<dim3((WB_TOTAL + 255) / 256), blk, 0, stream>>>(dw_w2, dw_w3, pw_w2, pw_w3,
                                                             sig_w1, sig_w2, sig_w3, wb);
    xcast_k<<<dim3(4608), blk, 0, stream>>>(x, xb16);
    // dw chain: 3 -> 64 -> 256 -> 576 (plane-major out)
    l1_k<<<dim3(144), blk, 0, stream>>>(pose, dw_w1, dw_b1, h1);
    gemm1x1<64,  false><<<dim3(576, 4), blk, 0, stream>>>(h1, w_dw2, dw_b2, h2, 256, 1);
    gemm1x1<256, true ><<<dim3(576, 9), blk, 0, stream>>>(h2, w_dw3, dw_b3, dwbuf, 576, 0);
    // pw chain: 3 -> 64 -> 256 -> 192 (plane-major out)
    l1_k<<<dim3(144), blk, 0, stream>>>(pose, pw_w1, pw_b1, h1);
    gemm1x1<64,  false><<<dim3(576, 4), blk, 0, stream>>>(h1, w_pw2, pw_b2, h2, 256, 1);
    gemm1x1<256, true ><<<dim3(576, 3), blk, 0, stream>>>(h2, w_pw3, pw_b3, pwbuf, 192, 0);
    // mean (LDS gather) + transpose for conv chain
    mean_k<<<dim3(36, 64), blk, 0, stream>>>(xb16, imy, imx, dwbuf, mean_cm);
    tr_k<<<dim3(576, 2), blk, 0, stream>>>(mean_cm, mean_pm);
    // sigma conv chain
    conv3x3_mfma<4><<<dim3(1152), blk, 0, stream>>>(mean_pm, w_s1t, sig_b1, s1, 1);
    conv3x3_mfma<4><<<dim3(1152), blk, 0, stream>>>(s1,      w_s2t, sig_b2, s2, 1);
    conv3x3_mfma<1><<<dim3(1152), blk, 0, stream>>>(s2,      w_s3t, sig_b3, sigma, 0);
    // xa (LDS gather), then einsum partial + reduce
    xa_k<<<dim3(36, 64), blk, 0, stream>>>(xb16, imy, imx, dwbuf, mean_cm, sigma, xab);
    einsum_part<<<dim3(144, 2, 4), blk, 0, stream>>>(xab, pwbuf, part);
    einsum_red<<<dim3(864), blk, 0, stream>>>(part, out);
}

// Round 5
// 286.007 us; speedup vs baseline: 3.7575x; 1.0400x over previous
//
#include <hip/hip_runtime.h>

#define NPIX 36864   // 192*192

typedef __attribute__((ext_vector_type(8))) short short8;
typedef __attribute__((ext_vector_type(4))) float float4v;

__device__ inline unsigned short f2b(float x) {
    unsigned int u = __float_as_uint(x);
    unsigned int r = (u + 0x7FFFu + ((u >> 16) & 1u)) >> 16;
    return (unsigned short)r;
}
__device__ inline float b2f(unsigned short h) {
    return __uint_as_float(((unsigned int)h) << 16);
}

// ---------------------------------------------------------------- fused weight-prep + x cast
//  wb layout (shorts):
//  [0      ) dw_w2 [256][64]        n=16384
//  [16384  ) dw_w3 [576][256]       n=147456
//  [163840 ) pw_w2 [256][64]        n=16384
//  [180224 ) pw_w3 [192][256]       n=49152
//  [229376 ) sigW1t [9][64][64]     n=36864   (tap-major)
//  [266240 ) sigW2t [9][64][64]     n=36864
//  [303104 ) sigW3t [9][16][64]     n=9216    (oc padded 2->16 with zeros)
#define WB_TOTAL 312320
#define XCAST_N  1179648   // 2*64*9216
__global__ __launch_bounds__(256) void prep_all(
    const float* __restrict__ dw2, const float* __restrict__ dw3,
    const float* __restrict__ pw2, const float* __restrict__ pw3,
    const float* __restrict__ sw1, const float* __restrict__ sw2,
    const float* __restrict__ sw3, unsigned short* __restrict__ wb,
    const float* __restrict__ x, unsigned short* __restrict__ xb)
{
    int i = blockIdx.x * 256 + threadIdx.x;
    if (i >= WB_TOTAL) {
        int j = i - WB_TOTAL;
        if (j < XCAST_N) xb[j] = f2b(x[j]);
        return;
    }
    unsigned short v;
    if (i < 16384)        v = f2b(dw2[i]);
    else if (i < 163840)  v = f2b(dw3[i - 16384]);
    else if (i < 180224)  v = f2b(pw2[i - 163840]);
    else if (i < 229376)  v = f2b(pw3[i - 180224]);
    else if (i < 266240) { int j = i - 229376; int t = j / 4096, r = j % 4096, oc = r / 64, ic = r % 64;
                           v = f2b(sw1[(oc * 64 + ic) * 9 + t]); }
    else if (i < 303104) { int j = i - 266240; int t = j / 4096, r = j % 4096, oc = r / 64, ic = r % 64;
                           v = f2b(sw2[(oc * 64 + ic) * 9 + t]); }
    else                 { int j = i - 303104; int t = j / 1024, r = j % 1024, oc = r / 64, ic = r % 64;
                           v = (oc < 2) ? f2b(sw3[(oc * 64 + ic) * 9 + t]) : (unsigned short)0; }
    wb[i] = v;
}

// ---------------------------------------------------------------- layer-1 1x1 (3 -> 64), both chains
// grid (144, 2 chains, 4 cgroups); out: [2][NPIX][64] pixel-major bf16
__global__ __launch_bounds__(256) void l1_k(
    const float* __restrict__ pose,
    const float* __restrict__ wA, const float* __restrict__ bA,
    const float* __restrict__ wB, const float* __restrict__ bB,
    unsigned short* __restrict__ out)
{
    int px = blockIdx.x * 256 + threadIdx.x;
    int chain = blockIdx.y;
    int cg = blockIdx.z * 16;
    const float* w = chain ? wB : wA;
    const float* bi = chain ? bB : bA;
    float p0 = pose[px], p1 = pose[NPIX + px], p2 = pose[2 * NPIX + px];
    unsigned int pk[8];
    #pragma unroll
    for (int c = 0; c < 16; ++c) {
        int cc = cg + c;
        float v = bi[cc] + w[cc * 3] * p0 + w[cc * 3 + 1] * p1 + w[cc * 3 + 2] * p2;
        v = fmaxf(v, 0.f);
        unsigned short u = f2b(v);
        if (c & 1) pk[c >> 1] |= ((unsigned int)u) << 16; else pk[c >> 1] = u;
    }
    uint4* o = (uint4*)&out[((size_t)chain * NPIX + px) * 64 + cg];
    o[0] = ((uint4*)pk)[0];
    o[1] = ((uint4*)pk)[1];
}

// ---------------------------------------------------------------- bf16 MFMA GEMM, dual-chain
// act: [NPIX][K] pixel-major; wgt: [OC][K]. grid.y < tilesA -> chain A else B.
// TR=0: out[px][octot] pixel-major. TR=1: out[oc][NPIX] plane-major.
template<int K, bool TR>
__global__ __launch_bounds__(256) void gemm_dual(
    const unsigned short* __restrict__ actA, const unsigned short* __restrict__ actB,
    const unsigned short* __restrict__ wgtA, const unsigned short* __restrict__ wgtB,
    const float* __restrict__ biasA, const float* __restrict__ biasB,
    unsigned short* __restrict__ outA, unsigned short* __restrict__ outB,
    int tilesA, int octotA, int octotB, int relu)
{
    constexpr int KP = K + 8;
    __shared__ unsigned short Bs[64 * KP];
    const int tid = threadIdx.x;
    const int px0 = blockIdx.x * 64;
    const bool second = (int)blockIdx.y >= tilesA;
    const int oc0 = (second ? blockIdx.y - tilesA : blockIdx.y) * 64;
    const unsigned short* act = second ? actB : actA;
    const unsigned short* wgt = second ? wgtB : wgtA;
    const float* bias = second ? biasB : biasA;
    unsigned short* outp = second ? outB : outA;
    const int octot = second ? octotB : octotA;
    for (int idx = tid; idx < 64 * (K / 8); idx += 256) {
        int p = idx / (K / 8), ko = (idx % (K / 8)) * 8;
        *(short8*)&Bs[p * KP + ko] = *(const short8*)&act[(size_t)(px0 + p) * K + ko];
    }
    __syncthreads();
    const int w = tid >> 6, l = tid & 63;
    const int ln = l & 15, lkg = l >> 4, lk = lkg * 8;
    float4v acc[4] = {{0,0,0,0},{0,0,0,0},{0,0,0,0},{0,0,0,0}};
    const int ocA = oc0 + w * 16 + ln;
    #pragma unroll
    for (int kc = 0; kc < K; kc += 32) {
        short8 a = *(const short8*)&wgt[(size_t)ocA * K + kc + lk];
        #pragma unroll
        for (int nt = 0; nt < 4; ++nt) {
            short8 b = *(const short8*)&Bs[(nt * 16 + ln) * KP + kc + lk];
            acc[nt] = __builtin_amdgcn_mfma_f32_16x16x32_bf16(a, b, acc[nt], 0, 0, 0);
        }
    }
    #pragma unroll
    for (int nt = 0; nt < 4; ++nt) {
        int px = px0 + nt * 16 + ln;
        int oc = oc0 + w * 16 + lkg * 4;
        float v[4];
        #pragma unroll
        for (int r = 0; r < 4; ++r) {
            v[r] = acc[nt][r] + bias[oc + r];
            if (relu) v[r] = fmaxf(v[r], 0.f);
        }
        if (TR) {
            #pragma unroll
            for (int r = 0; r < 4; ++r)
                outp[(size_t)(oc + r) * NPIX + px] = f2b(v[r]);
        } else {
            uint2 pk;
            pk.x = (unsigned int)f2b(v[0]) | (((unsigned int)f2b(v[1])) << 16);
            pk.y = (unsigned int)f2b(v[2]) | (((unsigned int)f2b(v[3])) << 16);
            *(uint2*)&outp[(size_t)px * octot + oc] = pk;
        }
    }
}

// ---------------------------------------------------------------- bf16 MFMA 3x3 conv
template<int MT>
__global__ __launch_bounds__(256) void conv3x3_mfma(
    const unsigned short* __restrict__ act, const unsigned short* __restrict__ wgt,
    const float* __restrict__ bias, unsigned short* __restrict__ out,
    int relu)
{
    constexpr int SP = 72;
    constexpr int OCP = MT * 16;
    __shared__ unsigned short Bs[3 * 66 * SP];
    const int tid = threadIdx.x;
    int bx = blockIdx.x;
    const int xt = bx % 3; bx /= 3;
    const int y = bx % 192; const int b = bx / 192;
    const int x0 = xt * 64;
    const size_t actb = (size_t)b * NPIX * 64;
    for (int s = tid; s < 198; s += 256) {
        int r = s / 66, i = s % 66;
        int yy = y + r - 1, xx = x0 + i - 1;
        unsigned short* dst = &Bs[(r * 66 + i) * SP];
        if (yy >= 0 && yy < 192 && xx >= 0 && xx < 192) {
            const unsigned short* src = &act[actb + (size_t)(yy * 192 + xx) * 64];
            #pragma unroll
            for (int j = 0; j < 8; ++j) *(short8*)(dst + j * 8) = *(const short8*)(src + j * 8);
        } else {
            short8 z = {};
            #pragma unroll
            for (int j = 0; j < 8; ++j) *(short8*)(dst + j * 8) = z;
        }
    }
    __syncthreads();
    const int w = tid >> 6, l = tid & 63;
    const int ln = l & 15, lkg = l >> 4, lk = lkg * 8;
    const int mt = (MT == 4) ? w : 0;
    const int NT = (MT == 4) ? 4 : 1;
    const int ntb = (MT == 4) ? 0 : w;
    float4v acc[4] = {{0,0,0,0},{0,0,0,0},{0,0,0,0},{0,0,0,0}};
    #pragma unroll
    for (int t = 0; t < 9; ++t) {
        const int r = t / 3, dx = t % 3;
        #pragma unroll
        for (int ic0 = 0; ic0 < 64; ic0 += 32) {
            short8 a = *(const short8*)&wgt[((size_t)t * OCP + mt * 16 + ln) * 64 + ic0 + lk];
            #pragma unroll
            for (int n = 0; n < 4; ++n) {
                if (n >= NT) break;
                int slot = r * 66 + (ntb + n) * 16 + ln + dx;
                short8 bf = *(const short8*)&Bs[slot * SP + ic0 + lk];
                acc[n] = __builtin_amdgcn_mfma_f32_16x16x32_bf16(a, bf, acc[n], 0, 0, 0);
            }
        }
    }
    #pragma unroll
    for (int n = 0; n < 4; ++n) {
        if (n >= NT) break;
        int px = y * 192 + x0 + (ntb + n) * 16 + ln;
        if (MT == 4) {
            int oc = mt * 16 + lkg * 4;
            float v0 = acc[n][0] + bias[oc + 0];
            float v1 = acc[n][1] + bias[oc + 1];
            float v2 = acc[n][2] + bias[oc + 2];
            float v3 = acc[n][3] + bias[oc + 3];
            if (relu) { v0 = fmaxf(v0, 0.f); v1 = fmaxf(v1, 0.f); v2 = fmaxf(v2, 0.f); v3 = fmaxf(v3, 0.f); }
            uint2 pk;
            pk.x = (unsigned int)f2b(v0) | (((unsigned int)f2b(v1)) << 16);
            pk.y = (unsigned int)f2b(v2) | (((unsigned int)f2b(v3)) << 16);
            *(uint2*)&out[((size_t)b * NPIX + px) * 64 + oc] = pk;
        } else if (lkg == 0) {
            float v0 = acc[n][0] + bias[0];
            float v1 = acc[n][1] + bias[1];
            out[((size_t)b * 2 + 0) * NPIX + px] = f2b(v0);
            out[((size_t)b * 2 + 1) * NPIX + px] = f2b(v1);
        }
    }
}

// ---------------------------------------------------------------- mean: LDS-resident plane gather
__global__ __launch_bounds__(256) void mean_k(
    const unsigned short* __restrict__ xb, const int* __restrict__ imy, const int* __restrict__ imx,
    const unsigned short* __restrict__ dw, unsigned short* __restrict__ mean_cm)
{
    __shared__ unsigned short pl[2][9216];
    const int c = blockIdx.y;
    const int px0 = blockIdx.x * 1024;
    const int tid = threadIdx.x;
    {
        const short8* s0 = (const short8*)(xb + (size_t)c * 9216);
        const short8* s1 = (const short8*)(xb + (size_t)(64 + c) * 9216);
        short8* d0 = (short8*)pl[0];
        short8* d1 = (short8*)pl[1];
        for (int i = tid; i < 1152; i += 256) { d0[i] = s0[i]; d1[i] = s1[i]; }
    }
    __syncthreads();
    #pragma unroll
    for (int q = 0; q < 4; ++q) {
        int px = px0 + q * 256 + tid;
        int iy = imy[px], ix = imx[px];
        float wk[9];
        {
            float d[9];
            #pragma unroll
            for (int k = 0; k < 9; ++k) d[k] = b2f(dw[(size_t)(c * 9 + k) * NPIX + px]);
            float m = d[0];
            #pragma unroll
            for (int k = 1; k < 9; ++k) m = fmaxf(m, d[k]);
            float s = 0.f;
            #pragma unroll
            for (int k = 0; k < 9; ++k) { wk[k] = __expf(d[k] - m); s += wk[k]; }
            float inv = 1.f / s;
            #pragma unroll
            for (int k = 0; k < 9; ++k) wk[k] *= inv;
        }
        #pragma unroll
        for (int b = 0; b < 2; ++b) {
            float a = 0.f;
            #pragma unroll
            for (int k = 0; k < 9; ++k) {
                int yy = iy + k / 3 - 1, xx = ix + k % 3 - 1;
                float h = (yy >= 0 && yy < 96 && xx >= 0 && xx < 96) ? b2f(pl[b][yy * 96 + xx]) : 0.f;
                a += wk[k] * h;
            }
            mean_cm[(size_t)(b * 64 + c) * NPIX + px] = f2b(a);
        }
    }
}

// ---------------------------------------------------------------- transpose [2][64][NPIX] -> [2][NPIX][64]
__global__ __launch_bounds__(256) void tr_k(
    const unsigned short* __restrict__ in, unsigned short* __restrict__ out)
{
    __shared__ unsigned short T[64 * 68];
    int px0 = blockIdx.x * 64;
    int b = blockIdx.y;
    int tid = threadIdx.x;
    for (int i = tid; i < 4096; i += 256) {
        int c = i >> 6, p = i & 63;
        T[p * 68 + c] = in[(size_t)(b * 64 + c) * NPIX + px0 + p];
    }
    __syncthreads();
    for (int i = tid; i < 4096; i += 256) {
        int p = i >> 6, c = i & 63;
        out[((size_t)b * NPIX + px0 + p) * 64 + c] = T[p * 68 + c];
    }
}

// ---------------------------------------------------------------- xa: LDS-resident plane gather
__global__ __launch_bounds__(256) void xa_k(
    const unsigned short* __restrict__ xb, const int* __restrict__ imy, const int* __restrict__ imx,
    const unsigned short* __restrict__ dw, const unsigned short* __restrict__ mean_cm,
    const unsigned short* __restrict__ sigma, unsigned short* __restrict__ xab)
{
    __shared__ unsigned short pl[2][9216];
    const int c = blockIdx.y;
    const int px0 = blockIdx.x * 1024;
    const int tid = threadIdx.x;
    {
        const short8* s0 = (const short8*)(xb + (size_t)c * 9216);
        const short8* s1 = (const short8*)(xb + (size_t)(64 + c) * 9216);
        short8* d0 = (short8*)pl[0];
        short8* d1 = (short8*)pl[1];
        for (int i = tid; i < 1152; i += 256) { d0[i] = s0[i]; d1[i] = s1[i]; }
    }
    __syncthreads();
    #pragma unroll
    for (int q = 0; q < 4; ++q) {
        int px = px0 + q * 256 + tid;
        int iy = imy[px], ix = imx[px];
        float d[9];
        #pragma unroll
        for (int k = 0; k < 9; ++k) d[k] = b2f(dw[(size_t)(c * 9 + k) * NPIX + px]);
        #pragma unroll
        for (int b = 0; b < 2; ++b) {
            float mn = b2f(mean_cm[(size_t)(b * 64 + c) * NPIX + px]);
            float sd = b2f(sigma[((size_t)b * 2 + 0) * NPIX + px]);
            float sr = b2f(sigma[((size_t)b * 2 + 1) * NPIX + px]);
            float h[9], bw[9];
            #pragma unroll
            for (int k = 0; k < 9; ++k) {
                int yy = iy + k / 3 - 1, xx = ix + k % 3 - 1;
                h[k] = (yy >= 0 && yy < 96 && xx >= 0 && xx < 96) ? b2f(pl[b][yy * 96 + xx]) : 0.f;
                bw[k] = sd * d[k] + sr * fabsf(h[k] - mn);
            }
            float m = bw[0];
            #pragma unroll
            for (int k = 1; k < 9; ++k) m = fmaxf(m, bw[k]);
            float s = 0.f, a = 0.f;
            #pragma unroll
            for (int k = 0; k < 9; ++k) { float e = __expf(bw[k] - m); s += e; a += e * h[k]; }
            xab[(size_t)(b * 64 + c) * NPIX + px] = f2b(a / s);
        }
    }
}

// ---------------------------------------------------------------- einsum partials over 16-c chunks
__global__ __launch_bounds__(256) void einsum_part(
    const unsigned short* __restrict__ xab, const unsigned short* __restrict__ pw,
    float* __restrict__ part)
{
    int px = blockIdx.x * 256 + threadIdx.x;
    int b = blockIdx.y;
    int c0 = blockIdx.z * 16;
    float a0 = 0.f, a1 = 0.f, a2 = 0.f;
    #pragma unroll
    for (int c = 0; c < 16; ++c) {
        float v = b2f(xab[(size_t)(b * 64 + c0 + c) * NPIX + px]);
        a0 += v * b2f(pw[(size_t)((c0 + c) * 3 + 0) * NPIX + px]);
        a1 += v * b2f(pw[(size_t)((c0 + c) * 3 + 1) * NPIX + px]);
        a2 += v * b2f(pw[(size_t)((c0 + c) * 3 + 2) * NPIX + px]);
    }
    size_t base = ((size_t)blockIdx.z * 6 + b * 3) * NPIX + px;
    part[base + 0 * NPIX] = a0;
    part[base + 1 * NPIX] = a1;
    part[base + 2 * NPIX] = a2;
}

__global__ __launch_bounds__(256) void einsum_red(
    const float* __restrict__ part, float* __restrict__ out)
{
    int i = blockIdx.x * 256 + threadIdx.x;   // over 6*NPIX
    float s = part[i] + part[(size_t)6 * NPIX + i] + part[(size_t)12 * NPIX + i] + part[(size_t)18 * NPIX + i];
    out[i] = s;
}

extern "C" void kernel_launch(void* const* d_in, const int* in_sizes, int n_in,
                              void* d_out, int out_size, void* d_ws, size_t ws_size,
                              hipStream_t stream)
{
    (void)in_sizes; (void)n_in; (void)out_size; (void)ws_size;
    const float* x      = (const float*)d_in[0];
    const float* pose   = (const float*)d_in[1];
    const int*   imy    = (const int*)d_in[2];
    const int*   imx    = (const int*)d_in[3];
    const float* sig_w1 = (const float*)d_in[4];
    const float* sig_b1 = (const float*)d_in[5];
    const float* sig_w2 = (const float*)d_in[6];
    const float* sig_b2 = (const float*)d_in[7];
    const float* sig_w3 = (const float*)d_in[8];
    const float* sig_b3 = (const float*)d_in[9];
    const float* dw_w1  = (const float*)d_in[10];
    const float* dw_b1  = (const float*)d_in[11];
    const float* dw_w2  = (const float*)d_in[12];
    const float* dw_b2  = (const float*)d_in[13];
    const float* dw_w3  = (const float*)d_in[14];
    const float* dw_b3  = (const float*)d_in[15];
    const float* pw_w1  = (const float*)d_in[16];
    const float* pw_b1  = (const float*)d_in[17];
    const float* pw_w2  = (const float*)d_in[18];
    const float* pw_b2  = (const float*)d_in[19];
    const float* pw_w3  = (const float*)d_in[20];
    const float* pw_b3  = (const float*)d_in[21];
    float* out = (float*)d_out;

    unsigned short* ws = (unsigned short*)d_ws;
    size_t off = 0;
    unsigned short* wb      = ws + off; off += WB_TOTAL;
    unsigned short* xb16    = ws + off; off += (size_t)XCAST_N;
    unsigned short* h1      = ws + off; off += (size_t)2 * NPIX * 64;   // [chain][px][64]
    unsigned short* h2      = ws + off; off += (size_t)2 * NPIX * 256;  // [chain][px][256]
    unsigned short* dwbuf   = ws + off; off += (size_t)576 * NPIX;      // plane-major
    unsigned short* pwbuf   = ws + off; off += (size_t)192 * NPIX;      // plane-major
    unsigned short* mean_cm = ws + off; off += (size_t)2 * 64 * NPIX;
    unsigned short* mean_pm = ws + off; off += (size_t)2 * NPIX * 64;
    unsigned short* s1      = ws + off; off += (size_t)2 * NPIX * 64;
    unsigned short* s2      = ws + off; off += (size_t)2 * NPIX * 64;
    unsigned short* sigma   = ws + off; off += (size_t)2 * 2 * NPIX;
    unsigned short* xab     = ws + off; off += (size_t)2 * 64 * NPIX;
    off = (off + 1) & ~(size_t)1;
    float* part = (float*)(ws + off);  // 4*6*NPIX floats

    unsigned short* w_dw2 = wb + 0;
    unsigned short* w_dw3 = wb + 16384;
    unsigned short* w_pw2 = wb + 163840;
    unsigned short* w_pw3 = wb + 180224;
    unsigned short* w_s1t = wb + 229376;
    unsigned short* w_s2t = wb + 266240;
    unsigned short* w_s3t = wb + 303104;

    unsigned short* h1dw = h1;
    unsigned short* h1pw = h1 + (size_t)NPIX * 64;
    unsigned short* h2dw = h2;
    unsigned short* h2pw = h2 + (size_t)NPIX * 256;

    dim3 blk(256);
    // weights + x cast (one dispatch)
    prep_all<<<dim3((WB_TOTAL + XCAST_N + 255) / 256), blk, 0, stream>>>(
        dw_w2, dw_w3, pw_w2, pw_w3, sig_w1, sig_w2, sig_w3, wb, x, xb16);
    // layer 1, both chains (one dispatch)
    l1_k<<<dim3(144, 2, 4), blk, 0, stream>>>(pose, dw_w1, dw_b1, pw_w1, pw_b1, h1);
    // layer 2 (64->256), both chains (one dispatch)
    gemm_dual<64, false><<<dim3(576, 8), blk, 0, stream>>>(
        h1dw, h1pw, w_dw2, w_pw2, dw_b2, pw_b2, h2dw, h2pw, 4, 256, 256, 1);
    // layer 3 (256->576 / 256->192), both chains, plane-major out (one dispatch)
    gemm_dual<256, true><<<dim3(576, 12), blk, 0, stream>>>(
        h2dw, h2pw, w_dw3, w_pw3, dw_b3, pw_b3, dwbuf, pwbuf, 9, 576, 192, 0);
    // mean (LDS gather) + transpose for conv chain
    mean_k<<<dim3(36, 64), blk, 0, stream>>>(xb16, imy, imx, dwbuf, mean_cm);
    tr_k<<<dim3(576, 2), blk, 0, stream>>>(mean_cm, mean_pm);
    // sigma conv chain
    conv3x3_mfma<4><<<dim3(1152), blk, 0, stream>>>(mean_pm, w_s1t, sig_b1, s1, 1);
    conv3x3_mfma<4><<<dim3(1152), blk, 0, stream>>>(s1,      w_s2t, sig_b2, s2, 1);
    conv3x3_mfma<1><<<dim3(1152), blk, 0, stream>>>(s2,      w_s3t, sig_b3, sigma, 0);
    // xa (LDS gather), einsum partial + reduce
    xa_k<<<dim3(36, 64), blk, 0, stream>>>(xb16, imy, imx, dwbuf, mean_cm, sigma, xab);
    einsum_part<<<dim3(144, 2, 4), blk, 0, stream>>>(xab, pwbuf, part);
    einsum_red<<<dim3(864), blk, 0, stream>>>(part, out);
}

// Round 6
// 280.887 us; speedup vs baseline: 3.8260x; 1.0182x over previous
//
#include <hip/hip_runtime.h>

#define NPIX 36864   // 192*192

typedef __attribute__((ext_vector_type(8))) short short8;
typedef __attribute__((ext_vector_type(4))) short short4v;
typedef __attribute__((ext_vector_type(4))) float float4v;

__device__ inline unsigned short f2b(float x) {
    unsigned int u = __float_as_uint(x);
    unsigned int r = (u + 0x7FFFu + ((u >> 16) & 1u)) >> 16;
    return (unsigned short)r;
}
__device__ inline float b2f(unsigned short h) {
    return __uint_as_float(((unsigned int)h) << 16);
}

// ---------------------------------------------------------------- fused weight-prep + x cast
//  wb layout (shorts):
//  [0      ) dw_w2 [256][64]        n=16384
//  [16384  ) pw_w2 [256][64]        n=16384
//  [32768  ) dw_w3 [576][256]       n=147456   } combined [768][256]
//  [180224 ) pw_w3 [192][256]       n=49152    }
//  [229376 ) sigW1t [9][64][64]     n=36864   (tap-major)
//  [266240 ) sigW2t [9][64][64]     n=36864
//  [303104 ) sigW3t [9][16][64]     n=9216    (oc padded 2->16 with zeros)
#define WB_TOTAL 312320
#define XCAST_N  1179648   // 2*64*9216
__global__ __launch_bounds__(256) void prep_all(
    const float* __restrict__ dw2, const float* __restrict__ dw3,
    const float* __restrict__ pw2, const float* __restrict__ pw3,
    const float* __restrict__ sw1, const float* __restrict__ sw2,
    const float* __restrict__ sw3, unsigned short* __restrict__ wb,
    const float* __restrict__ x, unsigned short* __restrict__ xb)
{
    int i = blockIdx.x * 256 + threadIdx.x;
    if (i >= WB_TOTAL) {
        int j = i - WB_TOTAL;
        if (j < XCAST_N) xb[j] = f2b(x[j]);
        return;
    }
    unsigned short v;
    if (i < 16384)        v = f2b(dw2[i]);
    else if (i < 32768)   v = f2b(pw2[i - 16384]);
    else if (i < 180224)  v = f2b(dw3[i - 32768]);
    else if (i < 229376)  v = f2b(pw3[i - 180224]);
    else if (i < 266240) { int j = i - 229376; int t = j / 4096, r = j % 4096, oc = r / 64, ic = r % 64;
                           v = f2b(sw1[(oc * 64 + ic) * 9 + t]); }
    else if (i < 303104) { int j = i - 266240; int t = j / 4096, r = j % 4096, oc = r / 64, ic = r % 64;
                           v = f2b(sw2[(oc * 64 + ic) * 9 + t]); }
    else                 { int j = i - 303104; int t = j / 1024, r = j % 1024, oc = r / 64, ic = r % 64;
                           v = (oc < 2) ? f2b(sw3[(oc * 64 + ic) * 9 + t]) : (unsigned short)0; }
    wb[i] = v;
}

// ---------------------------------------------------------------- layer-1 1x1 (3 -> 64), both chains
__global__ __launch_bounds__(256) void l1_k(
    const float* __restrict__ pose,
    const float* __restrict__ wA, const float* __restrict__ bA,
    const float* __restrict__ wB, const float* __restrict__ bB,
    unsigned short* __restrict__ out)
{
    int px = blockIdx.x * 256 + threadIdx.x;
    int chain = blockIdx.y;
    int cg = blockIdx.z * 16;
    const float* w = chain ? wB : wA;
    const float* bi = chain ? bB : bA;
    float p0 = pose[px], p1 = pose[NPIX + px], p2 = pose[2 * NPIX + px];
    unsigned int pk[8];
    #pragma unroll
    for (int c = 0; c < 16; ++c) {
        int cc = cg + c;
        float v = bi[cc] + w[cc * 3] * p0 + w[cc * 3 + 1] * p1 + w[cc * 3 + 2] * p2;
        v = fmaxf(v, 0.f);
        unsigned short u = f2b(v);
        if (c & 1) pk[c >> 1] |= ((unsigned int)u) << 16; else pk[c >> 1] = u;
    }
    uint4* o = (uint4*)&out[((size_t)chain * NPIX + px) * 64 + cg];
    o[0] = ((uint4*)pk)[0];
    o[1] = ((uint4*)pk)[1];
}

// ---------------------------------------------------------------- layer-2 bf16 MFMA GEMM, dual-chain (K=64)
template<int K>
__global__ __launch_bounds__(256) void gemm_dual(
    const unsigned short* __restrict__ actA, const unsigned short* __restrict__ actB,
    const unsigned short* __restrict__ wgtA, const unsigned short* __restrict__ wgtB,
    const float* __restrict__ biasA, const float* __restrict__ biasB,
    unsigned short* __restrict__ outA, unsigned short* __restrict__ outB,
    int tilesA, int octotA, int octotB, int relu)
{
    constexpr int KP = K + 8;
    __shared__ unsigned short Bs[64 * KP];
    const int tid = threadIdx.x;
    const int px0 = blockIdx.x * 64;
    const bool second = (int)blockIdx.y >= tilesA;
    const int oc0 = (second ? blockIdx.y - tilesA : blockIdx.y) * 64;
    const unsigned short* act = second ? actB : actA;
    const unsigned short* wgt = second ? wgtB : wgtA;
    const float* bias = second ? biasB : biasA;
    unsigned short* outp = second ? outB : outA;
    const int octot = second ? octotB : octotA;
    for (int idx = tid; idx < 64 * (K / 8); idx += 256) {
        int p = idx / (K / 8), ko = (idx % (K / 8)) * 8;
        *(short8*)&Bs[p * KP + ko] = *(const short8*)&act[(size_t)(px0 + p) * K + ko];
    }
    __syncthreads();
    const int w = tid >> 6, l = tid & 63;
    const int ln = l & 15, lkg = l >> 4, lk = lkg * 8;
    float4v acc[4] = {{0,0,0,0},{0,0,0,0},{0,0,0,0},{0,0,0,0}};
    const int ocA = oc0 + w * 16 + ln;
    #pragma unroll
    for (int kc = 0; kc < K; kc += 32) {
        short8 a = *(const short8*)&wgt[(size_t)ocA * K + kc + lk];
        #pragma unroll
        for (int nt = 0; nt < 4; ++nt) {
            short8 b = *(const short8*)&Bs[(nt * 16 + ln) * KP + kc + lk];
            acc[nt] = __builtin_amdgcn_mfma_f32_16x16x32_bf16(a, b, acc[nt], 0, 0, 0);
        }
    }
    #pragma unroll
    for (int nt = 0; nt < 4; ++nt) {
        int px = px0 + nt * 16 + ln;
        int oc = oc0 + w * 16 + lkg * 4;
        float v[4];
        #pragma unroll
        for (int r = 0; r < 4; ++r) {
            v[r] = acc[nt][r] + bias[oc + r];
            if (relu) v[r] = fmaxf(v[r], 0.f);
        }
        uint2 pk;
        pk.x = (unsigned int)f2b(v[0]) | (((unsigned int)f2b(v[1])) << 16);
        pk.y = (unsigned int)f2b(v[2]) | (((unsigned int)f2b(v[3])) << 16);
        *(uint2*)&outp[(size_t)px * octot + oc] = pk;
    }
}

// ---------------------------------------------------------------- layer-3 GEMM: [768][256] x [256][64px]
// grid (576, 4). M-tile 192 (wave owns 48 rows), N-tile 64 px, K=256.
// rows 0..575 (acts=h2dw) -> dwbuf plane-major; rows 576..767 (h2pw) -> pwbuf.
__global__ __launch_bounds__(256, 4) void gemm_l3(
    const unsigned short* __restrict__ actA, const unsigned short* __restrict__ actB,
    const unsigned short* __restrict__ wgt,
    const float* __restrict__ biasA, const float* __restrict__ biasB,
    unsigned short* __restrict__ outA, unsigned short* __restrict__ outB)
{
    __shared__ unsigned short Bs[64 * 264];      // 33792 B; reused as Ts[192][72]
    unsigned short* Ts = Bs;
    const int tid = threadIdx.x;
    const int px0 = blockIdx.x * 64;
    const int mb  = blockIdx.y;                  // 0..3
    const unsigned short* act = (mb < 3) ? actA : actB;
    for (int idx = tid; idx < 64 * 32; idx += 256) {
        int p = idx >> 5, ko = (idx & 31) * 8;
        *(short8*)&Bs[p * 264 + ko] = *(const short8*)&act[(size_t)(px0 + p) * 256 + ko];
    }
    __syncthreads();
    const int w = tid >> 6, l = tid & 63;
    const int ln = l & 15, lkg = l >> 4, lk = lkg * 8;
    const int row0 = mb * 192 + w * 48 + ln;     // A row for mt=0
    float4v acc[3][4] = {};
    #pragma unroll
    for (int kc = 0; kc < 256; kc += 32) {
        short8 a0 = *(const short8*)&wgt[(size_t)(row0 +  0) * 256 + kc + lk];
        short8 a1 = *(const short8*)&wgt[(size_t)(row0 + 16) * 256 + kc + lk];
        short8 a2 = *(const short8*)&wgt[(size_t)(row0 + 32) * 256 + kc + lk];
        #pragma unroll
        for (int nt = 0; nt < 4; ++nt) {
            short8 b = *(const short8*)&Bs[(nt * 16 + ln) * 264 + kc + lk];
            acc[0][nt] = __builtin_amdgcn_mfma_f32_16x16x32_bf16(a0, b, acc[0][nt], 0, 0, 0);
            acc[1][nt] = __builtin_amdgcn_mfma_f32_16x16x32_bf16(a1, b, acc[1][nt], 0, 0, 0);
            acc[2][nt] = __builtin_amdgcn_mfma_f32_16x16x32_bf16(a2, b, acc[2][nt], 0, 0, 0);
        }
    }
    __syncthreads();   // done reading Bs; reuse as Ts
    #pragma unroll
    for (int mt = 0; mt < 3; ++mt) {
        #pragma unroll
        for (int nt = 0; nt < 4; ++nt) {
            int col = nt * 16 + ln;
            #pragma unroll
            for (int r = 0; r < 4; ++r) {
                int row = w * 48 + mt * 16 + lkg * 4 + r;
                int goc = mb * 192 + row;
                float bv = (goc < 576) ? biasA[goc] : biasB[goc - 576];
                Ts[row * 72 + col] = f2b(acc[mt][nt][r] + bv);
            }
        }
    }
    __syncthreads();
    for (int i = tid; i < 1536; i += 256) {
        int row = i >> 3, ch = (i & 7) * 8;
        int goc = mb * 192 + row;
        unsigned short* dst = (goc < 576) ? (outA + (size_t)goc * NPIX)
                                          : (outB + (size_t)(goc - 576) * NPIX);
        *(short8*)&dst[px0 + ch] = *(const short8*)&Ts[row * 72 + ch];
    }
}

// ---------------------------------------------------------------- bf16 MFMA 3x3 conv
template<int MT>
__global__ __launch_bounds__(256) void conv3x3_mfma(
    const unsigned short* __restrict__ act, const unsigned short* __restrict__ wgt,
    const float* __restrict__ bias, unsigned short* __restrict__ out,
    int relu)
{
    constexpr int SP = 72;
    constexpr int OCP = MT * 16;
    __shared__ unsigned short Bs[3 * 66 * SP];
    const int tid = threadIdx.x;
    int bx = blockIdx.x;
    const int xt = bx % 3; bx /= 3;
    const int y = bx % 192; const int b = bx / 192;
    const int x0 = xt * 64;
    const size_t actb = (size_t)b * NPIX * 64;
    for (int s = tid; s < 198; s += 256) {
        int r = s / 66, i = s % 66;
        int yy = y + r - 1, xx = x0 + i - 1;
        unsigned short* dst = &Bs[(r * 66 + i) * SP];
        if (yy >= 0 && yy < 192 && xx >= 0 && xx < 192) {
            const unsigned short* src = &act[actb + (size_t)(yy * 192 + xx) * 64];
            #pragma unroll
            for (int j = 0; j < 8; ++j) *(short8*)(dst + j * 8) = *(const short8*)(src + j * 8);
        } else {
            short8 z = {};
            #pragma unroll
            for (int j = 0; j < 8; ++j) *(short8*)(dst + j * 8) = z;
        }
    }
    __syncthreads();
    const int w = tid >> 6, l = tid & 63;
    const int ln = l & 15, lkg = l >> 4, lk = lkg * 8;
    const int mt = (MT == 4) ? w : 0;
    const int NT = (MT == 4) ? 4 : 1;
    const int ntb = (MT == 4) ? 0 : w;
    float4v acc[4] = {{0,0,0,0},{0,0,0,0},{0,0,0,0},{0,0,0,0}};
    #pragma unroll
    for (int t = 0; t < 9; ++t) {
        const int r = t / 3, dx = t % 3;
        #pragma unroll
        for (int ic0 = 0; ic0 < 64; ic0 += 32) {
            short8 a = *(const short8*)&wgt[((size_t)t * OCP + mt * 16 + ln) * 64 + ic0 + lk];
            #pragma unroll
            for (int n = 0; n < 4; ++n) {
                if (n >= NT) break;
                int slot = r * 66 + (ntb + n) * 16 + ln + dx;
                short8 bf = *(const short8*)&Bs[slot * SP + ic0 + lk];
                acc[n] = __builtin_amdgcn_mfma_f32_16x16x32_bf16(a, bf, acc[n], 0, 0, 0);
            }
        }
    }
    #pragma unroll
    for (int n = 0; n < 4; ++n) {
        if (n >= NT) break;
        int px = y * 192 + x0 + (ntb + n) * 16 + ln;
        if (MT == 4) {
            int oc = mt * 16 + lkg * 4;
            float v0 = acc[n][0] + bias[oc + 0];
            float v1 = acc[n][1] + bias[oc + 1];
            float v2 = acc[n][2] + bias[oc + 2];
            float v3 = acc[n][3] + bias[oc + 3];
            if (relu) { v0 = fmaxf(v0, 0.f); v1 = fmaxf(v1, 0.f); v2 = fmaxf(v2, 0.f); v3 = fmaxf(v3, 0.f); }
            uint2 pk;
            pk.x = (unsigned int)f2b(v0) | (((unsigned int)f2b(v1)) << 16);
            pk.y = (unsigned int)f2b(v2) | (((unsigned int)f2b(v3)) << 16);
            *(uint2*)&out[((size_t)b * NPIX + px) * 64 + oc] = pk;
        } else if (lkg == 0) {
            float v0 = acc[n][0] + bias[0];
            float v1 = acc[n][1] + bias[1];
            out[((size_t)b * 2 + 0) * NPIX + px] = f2b(v0);
            out[((size_t)b * 2 + 1) * NPIX + px] = f2b(v1);
        }
    }
}

// ---------------------------------------------------------------- padded-plane LDS staging helper
// pl: [2][98*104] shorts, interior at [(y+1)*104 + x + 4]
#define PLSZ 10192   // 98*104
__device__ inline void stage_planes(const unsigned short* __restrict__ xb, int c,
                                    unsigned short* __restrict__ pl, int tid)
{
    short8 z = {};
    short8* pf = (short8*)pl;
    for (int i = tid; i < (2 * PLSZ) / 8; i += 256) pf[i] = z;
    __syncthreads();
    #pragma unroll
    for (int b = 0; b < 2; ++b) {
        const unsigned short* xp = xb + (size_t)(b * 64 + c) * 9216;
        unsigned short* pb = pl + b * PLSZ;
        for (int i = tid; i < 96 * 12; i += 256) {
            int row = i / 12, ch = i % 12;
            const short4v* src = (const short4v*)&xp[row * 96 + ch * 8];
            unsigned short* d = &pb[(row + 1) * 104 + 4 + ch * 8];
            *(short4v*)d = src[0];
            *(short4v*)(d + 4) = src[1];
        }
    }
    __syncthreads();
}

// ---------------------------------------------------------------- mean: padded LDS plane gather
__global__ __launch_bounds__(256) void mean_k(
    const unsigned short* __restrict__ xb, const int* __restrict__ imy, const int* __restrict__ imx,
    const unsigned short* __restrict__ dw, unsigned short* __restrict__ mean_cm)
{
    __shared__ unsigned short pl[2 * PLSZ];
    const int c = blockIdx.y;
    const int px0 = blockIdx.x * 1024;
    const int tid = threadIdx.x;
    stage_planes(xb, c, pl, tid);
    #pragma unroll
    for (int q = 0; q < 4; ++q) {
        int px = px0 + q * 256 + tid;
        int base = imy[px] * 104 + imx[px] + 3;
        float wk[9];
        {
            float d[9];
            #pragma unroll
            for (int k = 0; k < 9; ++k) d[k] = b2f(dw[(size_t)(c * 9 + k) * NPIX + px]);
            float m = d[0];
            #pragma unroll
            for (int k = 1; k < 9; ++k) m = fmaxf(m, d[k]);
            float s = 0.f;
            #pragma unroll
            for (int k = 0; k < 9; ++k) { wk[k] = __expf(d[k] - m); s += wk[k]; }
            float inv = 1.f / s;
            #pragma unroll
            for (int k = 0; k < 9; ++k) wk[k] *= inv;
        }
        #pragma unroll
        for (int b = 0; b < 2; ++b) {
            const unsigned short* pb = pl + b * PLSZ;
            float a = 0.f;
            #pragma unroll
            for (int k = 0; k < 9; ++k)
                a += wk[k] * b2f(pb[base + (k / 3) * 104 + (k % 3)]);
            mean_cm[(size_t)(b * 64 + c) * NPIX + px] = f2b(a);
        }
    }
}

// ---------------------------------------------------------------- transpose [2][64][NPIX] -> [2][NPIX][64]
__global__ __launch_bounds__(256) void tr_k(
    const unsigned short* __restrict__ in, unsigned short* __restrict__ out)
{
    __shared__ unsigned short T[64 * 68];
    int px0 = blockIdx.x * 64;
    int b = blockIdx.y;
    int tid = threadIdx.x;
    for (int i = tid; i < 4096; i += 256) {
        int c = i >> 6, p = i & 63;
        T[p * 68 + c] = in[(size_t)(b * 64 + c) * NPIX + px0 + p];
    }
    __syncthreads();
    for (int i = tid; i < 4096; i += 256) {
        int p = i >> 6, c = i & 63;
        out[((size_t)b * NPIX + px0 + p) * 64 + c] = T[p * 68 + c];
    }
}

// ---------------------------------------------------------------- xa: padded LDS plane gather
__global__ __launch_bounds__(256) void xa_k(
    const unsigned short* __restrict__ xb, const int* __restrict__ imy, const int* __restrict__ imx,
    const unsigned short* __restrict__ dw, const unsigned short* __restrict__ mean_cm,
    const unsigned short* __restrict__ sigma, unsigned short* __restrict__ xab)
{
    __shared__ unsigned short pl[2 * PLSZ];
    const int c = blockIdx.y;
    const int px0 = blockIdx.x * 1024;
    const int tid = threadIdx.x;
    stage_planes(xb, c, pl, tid);
    #pragma unroll
    for (int q = 0; q < 4; ++q) {
        int px = px0 + q * 256 + tid;
        int base = imy[px] * 104 + imx[px] + 3;
        float d[9];
        #pragma unroll
        for (int k = 0; k < 9; ++k) d[k] = b2f(dw[(size_t)(c * 9 + k) * NPIX + px]);
        #pragma unroll
        for (int b = 0; b < 2; ++b) {
            const unsigned short* pb = pl + b * PLSZ;
            float mn = b2f(mean_cm[(size_t)(b * 64 + c) * NPIX + px]);
            float sd = b2f(sigma[((size_t)b * 2 + 0) * NPIX + px]);
            float sr = b2f(sigma[((size_t)b * 2 + 1) * NPIX + px]);
            float h[9], bw[9];
            #pragma unroll
            for (int k = 0; k < 9; ++k) {
                h[k] = b2f(pb[base + (k / 3) * 104 + (k % 3)]);
                bw[k] = sd * d[k] + sr * fabsf(h[k] - mn);
            }
            float m = bw[0];
            #pragma unroll
            for (int k = 1; k < 9; ++k) m = fmaxf(m, bw[k]);
            float s = 0.f, a = 0.f;
            #pragma unroll
            for (int k = 0; k < 9; ++k) { float e = __expf(bw[k] - m); s += e; a += e * h[k]; }
            xab[(size_t)(b * 64 + c) * NPIX + px] = f2b(a / s);
        }
    }
}

// ---------------------------------------------------------------- einsum partials + reduce
__global__ __launch_bounds__(256) void einsum_part(
    const unsigned short* __restrict__ xab, const unsigned short* __restrict__ pw,
    float* __restrict__ part)
{
    int px = blockIdx.x * 256 + threadIdx.x;
    int b = blockIdx.y;
    int c0 = blockIdx.z * 16;
    float a0 = 0.f, a1 = 0.f, a2 = 0.f;
    #pragma unroll
    for (int c = 0; c < 16; ++c) {
        float v = b2f(xab[(size_t)(b * 64 + c0 + c) * NPIX + px]);
        a0 += v * b2f(pw[(size_t)((c0 + c) * 3 + 0) * NPIX + px]);
        a1 += v * b2f(pw[(size_t)((c0 + c) * 3 + 1) * NPIX + px]);
        a2 += v * b2f(pw[(size_t)((c0 + c) * 3 + 2) * NPIX + px]);
    }
    size_t base = ((size_t)blockIdx.z * 6 + b * 3) * NPIX + px;
    part[base + 0 * NPIX] = a0;
    part[base + 1 * NPIX] = a1;
    part[base + 2 * NPIX] = a2;
}

__global__ __launch_bounds__(256) void einsum_red(
    const float* __restrict__ part, float* __restrict__ out)
{
    int i = blockIdx.x * 256 + threadIdx.x;
    float s = part[i] + part[(size_t)6 * NPIX + i] + part[(size_t)12 * NPIX + i] + part[(size_t)18 * NPIX + i];
    out[i] = s;
}

extern "C" void kernel_launch(void* const* d_in, const int* in_sizes, int n_in,
                              void* d_out, int out_size, void* d_ws, size_t ws_size,
                              hipStream_t stream)
{
    (void)in_sizes; (void)n_in; (void)out_size; (void)ws_size;
    const float* x      = (const float*)d_in[0];
    const float* pose   = (const float*)d_in[1];
    const int*   imy    = (const int*)d_in[2];
    const int*   imx    = (const int*)d_in[3];
    const float* sig_w1 = (const float*)d_in[4];
    const float* sig_b1 = (const float*)d_in[5];
    const float* sig_w2 = (const float*)d_in[6];
    const float* sig_b2 = (const float*)d_in[7];
    const float* sig_w3 = (const float*)d_in[8];
    const float* sig_b3 = (const float*)d_in[9];
    const float* dw_w1  = (const float*)d_in[10];
    const float* dw_b1  = (const float*)d_in[11];
    const float* dw_w2  = (const float*)d_in[12];
    const float* dw_b2  = (const float*)d_in[13];
    const float* dw_w3  = (const float*)d_in[14];
    const float* dw_b3  = (const float*)d_in[15];
    const float* pw_w1  = (const float*)d_in[16];
    const float* pw_b1  = (const float*)d_in[17];
    const float* pw_w2  = (const float*)d_in[18];
    const float* pw_b2  = (const float*)d_in[19];
    const float* pw_w3  = (const float*)d_in[20];
    const float* pw_b3  = (const float*)d_in[21];
    float* out = (float*)d_out;

    unsigned short* ws = (unsigned short*)d_ws;
    size_t off = 0;
    unsigned short* wb      = ws + off; off += WB_TOTAL;
    unsigned short* xb16    = ws + off; off += (size_t)XCAST_N;
    unsigned short* h1      = ws + off; off += (size_t)2 * NPIX * 64;   // [chain][px][64]
    unsigned short* h2      = ws + off; off += (size_t)2 * NPIX * 256;  // [chain][px][256]
    unsigned short* dwbuf   = ws + off; off += (size_t)576 * NPIX;      // plane-major
    unsigned short* pwbuf   = ws + off; off += (size_t)192 * NPIX;      // plane-major
    unsigned short* mean_cm = ws + off; off += (size_t)2 * 64 * NPIX;
    unsigned short* mean_pm = ws + off; off += (size_t)2 * NPIX * 64;
    unsigned short* s1      = ws + off; off += (size_t)2 * NPIX * 64;
    unsigned short* s2      = ws + off; off += (size_t)2 * NPIX * 64;
    unsigned short* sigma   = ws + off; off += (size_t)2 * 2 * NPIX;
    unsigned short* xab     = ws + off; off += (size_t)2 * 64 * NPIX;
    off = (off + 1) & ~(size_t)1;
    float* part = (float*)(ws + off);  // 4*6*NPIX floats

    unsigned short* w_dw2 = wb + 0;
    unsigned short* w_pw2 = wb + 16384;
    unsigned short* w_33  = wb + 32768;   // combined [768][256]
    unsigned short* w_s1t = wb + 229376;
    unsigned short* w_s2t = wb + 266240;
    unsigned short* w_s3t = wb + 303104;

    unsigned short* h1dw = h1;
    unsigned short* h1pw = h1 + (size_t)NPIX * 64;
    unsigned short* h2dw = h2;
    unsigned short* h2pw = h2 + (size_t)NPIX * 256;

    dim3 blk(256);
    prep_all<<<dim3((WB_TOTAL + XCAST_N + 255) / 256), blk, 0, stream>>>(
        dw_w2, dw_w3, pw_w2, pw_w3, sig_w1, sig_w2, sig_w3, wb, x, xb16);
    l1_k<<<dim3(144, 2, 4), blk, 0, stream>>>(pose, dw_w1, dw_b1, pw_w1, pw_b1, h1);
    gemm_dual<64><<<dim3(576, 8), blk, 0, stream>>>(
        h1dw, h1pw, w_dw2, w_pw2, dw_b2, pw_b2, h2dw, h2pw, 4, 256, 256, 1);
    gemm_l3<<<dim3(576, 4), blk, 0, stream>>>(
        h2dw, h2pw, w_33, dw_b3, pw_b3, dwbuf, pwbuf);
    mean_k<<<dim3(36, 64), blk, 0, stream>>>(xb16, imy, imx, dwbuf, mean_cm);
    tr_k<<<dim3(576, 2), blk, 0, stream>>>(mean_cm, mean_pm);
    conv3x3_mfma<4><<<dim3(1152), blk, 0, stream>>>(mean_pm, w_s1t, sig_b1, s1, 1);
    conv3x3_mfma<4><<<dim3(1152), blk, 0, stream>>>(s1,      w_s2t, sig_b2, s2, 1);
    conv3x3_mfma<1><<<dim3(1152), blk, 0, stream>>>(s2,      w_s3t, sig_b3, sigma, 0);
    xa_k<<<dim3(36, 64), blk, 0, stream>>>(xb16, imy, imx, dwbuf, mean_cm, sigma, xab);
    einsum_part<<<dim3(144, 2, 4), blk, 0, stream>>>(xab, pwbuf, part);
    einsum_red<<<dim3(864), blk, 0, stream>>>(part, out);
}